// Round 3
// baseline (405.910 us; speedup 1.0000x reference)
//
#include <hip/hip_runtime.h>
#include <hip/hip_bf16.h>

typedef unsigned short ushort_t;
typedef __bf16 bf16x8 __attribute__((ext_vector_type(8)));
typedef float f32x4 __attribute__((ext_vector_type(4)));
typedef unsigned short us8 __attribute__((ext_vector_type(8)));
typedef unsigned short us4 __attribute__((ext_vector_type(4)));

#define HW 16384
#define CDIM 192
#define QKVC 576

static __device__ __forceinline__ float b2f(unsigned short u) {
    union { unsigned int i; float f; } cv; cv.i = ((unsigned int)u) << 16; return cv.f;
}
static __device__ __forceinline__ unsigned short f2b(float f) {
    union { __bf16 h; unsigned short u; } cv; cv.h = (__bf16)f; return cv.u;
}

// ---------------------------------------------------------------------------
// K0: one-time fp32 -> bf16 convert (wqkv weights), 8 elems/thread
// ---------------------------------------------------------------------------
__global__ __launch_bounds__(256) void k_cvt(const float* __restrict__ src,
                                             ushort_t* __restrict__ dst, int n8) {
    int i = blockIdx.x * 256 + threadIdx.x;
    if (i >= n8) return;
    f32x4 a = *(const f32x4*)&src[i * 8];
    f32x4 b = *(const f32x4*)&src[i * 8 + 4];
    us8 o;
#pragma unroll
    for (int e = 0; e < 4; ++e) { o[e] = f2b(a[e]); o[4 + e] = f2b(b[e]); }
    *(us8*)&dst[i * 8] = o;
}

// ---------------------------------------------------------------------------
// K1: depthwise 3x3 (fp32) on x + unbiased variance over HxW per (b,c)
// plane staged in LDS fp32 with +4 row pad (bank spread) + zero row
// also emits bf16 copy of x (xb) for the qkv GEMM's B-panel
// ---------------------------------------------------------------------------
__global__ __launch_bounds__(256) void k_dwvar(const float* __restrict__ x,
                                               const float* __restrict__ wdw,
                                               float* __restrict__ var,
                                               ushort_t* __restrict__ xb) {
    __shared__ __align__(16) float pl[128 * 132 + 132];   // rows stride 132, zero row at 16896
    __shared__ float red[8];
    int bc = blockIdx.x;                // b*192 + c
    int c = bc % CDIM;
    const float* xp = x + (size_t)bc * HW;
    ushort_t* xbp = xb + (size_t)bc * HW;
    int t = threadIdx.x;
#pragma unroll
    for (int i = 0; i < 16; ++i) {
        int gi = t + i * 256;           // float4 index [0,4096)
        int y = gi >> 5, xq = (gi & 31) << 2;
        f32x4 v4 = *(const f32x4*)&xp[gi * 4];
        *(f32x4*)&pl[y * 132 + xq] = v4;
        us4 b4;
#pragma unroll
        for (int j = 0; j < 4; ++j) b4[j] = f2b(v4[j]);
        *(us4*)&xbp[gi * 4] = b4;
    }
    if (t < 33) { f32x4 zz = {0.f, 0.f, 0.f, 0.f}; *(f32x4*)&pl[16896 + t * 4] = zz; }
    float w[9];
#pragma unroll
    for (int j = 0; j < 9; ++j) w[j] = wdw[c * 9 + j];
    __syncthreads();

    int y = t >> 1, xs = (t & 1) * 64;
    int yb0 = (y > 0)   ? (y - 1) * 132 : 16896;
    int yb1 = y * 132;
    int yb2 = (y < 127) ? (y + 1) * 132 : 16896;
    float l0 = 0.f, l1 = 0.f, l2 = 0.f;
    if (xs != 0) { l0 = pl[yb0 + 63]; l1 = pl[yb1 + 63]; l2 = pl[yb2 + 63]; }
    float s1 = 0.f, s2 = 0.f;
#pragma unroll
    for (int g = 0; g < 8; ++g) {
        int x0 = xs + g * 8;
        float e0[10], e1[10], e2[10];
        e0[0] = l0; e1[0] = l1; e2[0] = l2;
        f32x4 a0 = *(const f32x4*)&pl[yb0 + x0], b0 = *(const f32x4*)&pl[yb0 + x0 + 4];
        f32x4 a1 = *(const f32x4*)&pl[yb1 + x0], b1 = *(const f32x4*)&pl[yb1 + x0 + 4];
        f32x4 a2 = *(const f32x4*)&pl[yb2 + x0], b2 = *(const f32x4*)&pl[yb2 + x0 + 4];
#pragma unroll
        for (int j = 0; j < 4; ++j) {
            e0[1 + j] = a0[j]; e0[5 + j] = b0[j];
            e1[1 + j] = a1[j]; e1[5 + j] = b1[j];
            e2[1 + j] = a2[j]; e2[5 + j] = b2[j];
        }
        float r0 = 0.f, r1 = 0.f, r2 = 0.f;
        if (x0 + 8 < 128) { r0 = pl[yb0 + x0 + 8]; r1 = pl[yb1 + x0 + 8]; r2 = pl[yb2 + x0 + 8]; }
        e0[9] = r0; e1[9] = r1; e2[9] = r2;
#pragma unroll
        for (int j = 0; j < 8; ++j) {
            float o = e0[j] * w[0] + e0[j + 1] * w[1] + e0[j + 2] * w[2]
                    + e1[j] * w[3] + e1[j + 1] * w[4] + e1[j + 2] * w[5]
                    + e2[j] * w[6] + e2[j + 1] * w[7] + e2[j + 2] * w[8];
            s1 += o; s2 += o * o;
        }
        l0 = e0[8]; l1 = e1[8]; l2 = e2[8];
    }
#pragma unroll
    for (int off = 32; off; off >>= 1) { s1 += __shfl_xor(s1, off); s2 += __shfl_xor(s2, off); }
    int wv = t >> 6;
    if ((t & 63) == 0) { red[wv * 2] = s1; red[wv * 2 + 1] = s2; }
    __syncthreads();
    if (t == 0) {
        float S1 = red[0] + red[2] + red[4] + red[6];
        float S2 = red[1] + red[3] + red[5] + red[7];
        var[bc] = (S2 - S1 * S1 * (1.0f / 16384.f)) * (1.0f / 16383.f);
    }
}

// ---------------------------------------------------------------------------
// K3: depthwise 3x3 on qkv planes (bf16 in/out, fp32 math/weights) + sum-sq
// LDS rows stride 136 bf16 (+8 pad) + zero row at 17408
// ---------------------------------------------------------------------------
__global__ __launch_bounds__(256) void k_dwqkv(const ushort_t* __restrict__ qkvraw,
                                               const float* __restrict__ wqd,
                                               ushort_t* __restrict__ qkvd,
                                               float* __restrict__ ssq) {
    __shared__ __align__(16) ushort_t pl[128 * 136 + 136];
    __shared__ float red[4];
    int bo = blockIdx.x;               // b*576 + o
    int o = bo % QKVC, b = bo / QKVC;
    const ushort_t* xp = qkvraw + (size_t)bo * HW;
    ushort_t* op = qkvd + (size_t)bo * HW;
    int t = threadIdx.x;
#pragma unroll
    for (int i = 0; i < 8; ++i) {
        int gi = t + i * 256;           // us8 index [0,2048)
        int y = gi >> 4, xo = (gi & 15) * 8;
        *(us8*)&pl[y * 136 + xo] = *(const us8*)&xp[gi * 8];
    }
    if (t < 17) { us8 zz = {}; *(us8*)&pl[17408 + t * 8] = zz; }
    float w[9];
#pragma unroll
    for (int j = 0; j < 9; ++j) w[j] = wqd[o * 9 + j];
    __syncthreads();

    int y = t >> 1, xs = (t & 1) * 64;
    int yb0 = (y > 0)   ? (y - 1) * 136 : 17408;
    int yb1 = y * 136;
    int yb2 = (y < 127) ? (y + 1) * 136 : 17408;
    float l0 = 0.f, l1 = 0.f, l2 = 0.f;
    if (xs != 0) { l0 = b2f(pl[yb0 + 63]); l1 = b2f(pl[yb1 + 63]); l2 = b2f(pl[yb2 + 63]); }
    float s2 = 0.f;
#pragma unroll
    for (int g = 0; g < 8; ++g) {
        int x0 = xs + g * 8;
        us8 v0 = *(const us8*)&pl[yb0 + x0];
        us8 v1 = *(const us8*)&pl[yb1 + x0];
        us8 v2 = *(const us8*)&pl[yb2 + x0];
        float r0 = 0.f, r1 = 0.f, r2 = 0.f;
        if (x0 + 8 < 128) { r0 = b2f(pl[yb0 + x0 + 8]); r1 = b2f(pl[yb1 + x0 + 8]); r2 = b2f(pl[yb2 + x0 + 8]); }
        float e0[10], e1[10], e2[10];
        e0[0] = l0; e1[0] = l1; e2[0] = l2;
#pragma unroll
        for (int j = 0; j < 8; ++j) { e0[j + 1] = b2f(v0[j]); e1[j + 1] = b2f(v1[j]); e2[j + 1] = b2f(v2[j]); }
        e0[9] = r0; e1[9] = r1; e2[9] = r2;
        us8 ob;
#pragma unroll
        for (int j = 0; j < 8; ++j) {
            float ov = e0[j] * w[0] + e0[j + 1] * w[1] + e0[j + 2] * w[2]
                     + e1[j] * w[3] + e1[j + 1] * w[4] + e1[j + 2] * w[5]
                     + e2[j] * w[6] + e2[j + 1] * w[7] + e2[j + 2] * w[8];
            unsigned short bits = f2b(ov);
            ob[j] = bits;
            float rv = b2f(bits);
            s2 += rv * rv;
        }
        *(us8*)&op[(size_t)y * 128 + x0] = ob;
        l0 = e0[8]; l1 = e1[8]; l2 = e2[8];
    }
    if (o < 2 * CDIM) {
#pragma unroll
        for (int off = 32; off; off >>= 1) s2 += __shfl_xor(s2, off);
        int wv = t >> 6;
        if ((t & 63) == 0) red[wv] = s2;
        __syncthreads();
        if (t == 0) ssq[b * 384 + o] = red[0] + red[1] + red[2] + red[3];
    }
}

// ---------------------------------------------------------------------------
// GEMM: C[b] = A[b] (MxK bf16, row-major) * B[b] (KxN bf16, N contiguous)
// BM=192 BN=128 BK=64; 4 waves x 3 row-tiles x 8 col-tiles; 16x16x32 bf16
// As: row-XOR swizzle. Bs: granule swizzle g_store = (k>>3) ^ ((n>>4)^n)&7
// -> conflict-free b128 reads (8 dwords/bank ideal), ~free stores
// ---------------------------------------------------------------------------
template<int CF>
__global__ __launch_bounds__(256) void k_gemm(const ushort_t* __restrict__ Av, long sAb,
                                              const ushort_t* __restrict__ Bv, long sBb,
                                              void* __restrict__ Cv, long sCb, int K) {
    __shared__ __align__(16) ushort_t As[192 * 64];
    __shared__ __align__(16) ushort_t Bs[128 * 64];
    int t = threadIdx.x;
    int wv = t >> 6, lane = t & 63, quad = lane >> 4, l15 = lane & 15;
    size_t aoff = (size_t)blockIdx.z * sAb + (size_t)blockIdx.y * 192 * K;
    size_t boff = (size_t)blockIdx.z * sBb + (size_t)blockIdx.x * 128;
    size_t coff = (size_t)blockIdx.z * sCb + (size_t)blockIdx.y * 192 * HW + (size_t)blockIdx.x * 128;
    f32x4 acc[24] = {};
    int bkr = t >> 3, bn0 = (t & 7) * 16, tlow = t & 7;   // tlow = n>>4 for this thread's n
    for (int kk = 0; kk < K; kk += 64) {
        // --- A stage: 192 rows x 64 k, 6 us8 slots per thread, row-XOR swizzle ---
#pragma unroll
        for (int i = 0; i < 6; ++i) {
            int s = t + i * 256;                   // [0,1536)
            int row = s >> 3, kc = (s & 7) * 8;
            int kcs = kc ^ ((row & 7) * 8);
            *(uint4*)&As[row * 64 + kcs] = *(const uint4*)&Av[aoff + (size_t)row * K + kk + kc];
        }
        // --- B stage: 2 k-rows per thread, transpose into [n][k] granule-swizzled ---
        const ushort_t* Bp = Bv + boff;
#pragma unroll
        for (int h = 0; h < 2; ++h) {
            int krow = bkr + h * 32;               // [0,64)
            int gk = krow >> 3, klo = krow & 7;
            us8 t0 = *(const us8*)&Bp[(size_t)(kk + krow) * HW + bn0];
            us8 t1 = *(const us8*)&Bp[(size_t)(kk + krow) * HW + bn0 + 8];
#pragma unroll
            for (int e = 0; e < 8; ++e) {
                int col = ((gk ^ tlow ^ e) << 3) + klo;   // f(n) = ((n>>4)^n)&7 = tlow^e
                Bs[(bn0 + e) * 64 + col] = t0[e];
                Bs[(bn0 + 8 + e) * 64 + col] = t1[e];
            }
        }
        __syncthreads();
#pragma unroll
        for (int s = 0; s < 2; ++s) {
            int r0 = wv * 16 + l15, r1 = 64 + r0, r2 = 128 + r0;
            int ko = s * 32 + quad * 8;
            bf16x8 af0 = *(const bf16x8*)&As[r0 * 64 + (ko ^ ((r0 & 7) * 8))];
            bf16x8 af1 = *(const bf16x8*)&As[r1 * 64 + (ko ^ ((r1 & 7) * 8))];
            bf16x8 af2 = *(const bf16x8*)&As[r2 * 64 + (ko ^ ((r2 & 7) * 8))];
#pragma unroll
            for (int tc = 0; tc < 8; ++tc) {
                int n = tc * 16 + l15;
                int g = (s * 4 + quad) ^ ((tc ^ l15) & 7);   // stored granule for true k-granule
                bf16x8 bfr = *(const bf16x8*)&Bs[n * 64 + (g << 3)];
                acc[tc]      = __builtin_amdgcn_mfma_f32_16x16x32_bf16(af0, bfr, acc[tc],      0, 0, 0);
                acc[8 + tc]  = __builtin_amdgcn_mfma_f32_16x16x32_bf16(af1, bfr, acc[8 + tc],  0, 0, 0);
                acc[16 + tc] = __builtin_amdgcn_mfma_f32_16x16x32_bf16(af2, bfr, acc[16 + tc], 0, 0, 0);
            }
        }
        __syncthreads();
    }
#pragma unroll
    for (int rt = 0; rt < 3; ++rt)
#pragma unroll
        for (int tc = 0; tc < 8; ++tc)
#pragma unroll
            for (int r = 0; r < 4; ++r) {
                int row = rt * 64 + wv * 16 + quad * 4 + r;
                size_t idx = coff + (size_t)row * HW + tc * 16 + l15;
                if (CF) ((float*)Cv)[idx] = acc[rt * 8 + tc][r];
                else    ((ushort_t*)Cv)[idx] = f2b(acc[rt * 8 + tc][r]);
            }
}

// ---------------------------------------------------------------------------
// K4: Gram G[b,h] = q . k^T (24x24, K=16384), LDS-staged, mfma, atomic combine
// ---------------------------------------------------------------------------
__global__ __launch_bounds__(256) void k_gram(const ushort_t* __restrict__ qkvd,
                                              float* __restrict__ G) {
    __shared__ __align__(16) ushort_t qs[24 * 264];
    __shared__ __align__(16) ushort_t ks[24 * 264];
    int bh = blockIdx.y;
    int b = bh >> 3, h = bh & 7;
    int t = threadIdx.x, wv = t >> 6, lane = t & 63, quad = lane >> 4, l15 = lane & 15;
    const ushort_t* qb = qkvd + (size_t)b * 9437184 + (size_t)(h * 24) * HW;
    const ushort_t* kp = qb + (size_t)CDIM * HW;
    f32x4 a00 = {}, a01 = {}, a10 = {}, a11 = {};
    bf16x8 z = {};
    bool hi = (l15 < 8);
    int kbase0 = blockIdx.x * 2048;
    for (int sub = 0; sub < 8; ++sub) {
        int kbase = kbase0 + sub * 256;
#pragma unroll
        for (int j = 0; j < 3; ++j) {
            int gi = t + j * 256;       // [0,768)
            int row = gi >> 5, c8 = (gi & 31) * 8;
            *(us8*)&qs[row * 264 + c8] = *(const us8*)&qb[(size_t)row * HW + kbase + c8];
            *(us8*)&ks[row * 264 + c8] = *(const us8*)&kp[(size_t)row * HW + kbase + c8];
        }
        __syncthreads();
#pragma unroll
        for (int s = 0; s < 2; ++s) {
            int ko = (wv * 2 + s) * 32 + quad * 8;
            bf16x8 qa0 = *(const bf16x8*)&qs[l15 * 264 + ko];
            bf16x8 qa1 = hi ? *(const bf16x8*)&qs[(16 + l15) * 264 + ko] : z;
            bf16x8 kb0 = *(const bf16x8*)&ks[l15 * 264 + ko];
            bf16x8 kb1 = hi ? *(const bf16x8*)&ks[(16 + l15) * 264 + ko] : z;
            a00 = __builtin_amdgcn_mfma_f32_16x16x32_bf16(qa0, kb0, a00, 0, 0, 0);
            a01 = __builtin_amdgcn_mfma_f32_16x16x32_bf16(qa0, kb1, a01, 0, 0, 0);
            a10 = __builtin_amdgcn_mfma_f32_16x16x32_bf16(qa1, kb0, a10, 0, 0, 0);
            a11 = __builtin_amdgcn_mfma_f32_16x16x32_bf16(qa1, kb1, a11, 0, 0, 0);
        }
        __syncthreads();
    }
    float* Gp = G + (size_t)bh * 576;
#pragma unroll
    for (int r = 0; r < 4; ++r) {
        int r0 = quad * 4 + r, r1 = 16 + quad * 4 + r;
        int c0 = l15, c1 = 16 + l15;
        atomicAdd(&Gp[r0 * 24 + c0], a00[r]);
        if (c1 < 24) atomicAdd(&Gp[r0 * 24 + c1], a01[r]);
        if (r1 < 24) atomicAdd(&Gp[r1 * 24 + c0], a10[r]);
        if (r1 < 24 && c1 < 24) atomicAdd(&Gp[r1 * 24 + c1], a11[r]);
    }
}

// ---------------------------------------------------------------------------
// K5: softmax(P) per (b,h) and Weff[b] = W_proj * blockdiag(P)  (Weff bf16)
// grid (8, 24): each block redoes the cheap softmax, emits 1/24 of Weff
// ---------------------------------------------------------------------------
__global__ __launch_bounds__(256) void k_smweff(const float* __restrict__ G,
                                                const float* __restrict__ ssq,
                                                const float* __restrict__ var,
                                                const float* __restrict__ wproj,
                                                const float* __restrict__ temp,
                                                const float* __restrict__ resc,
                                                ushort_t* __restrict__ Weff) {
    int b = blockIdx.x, t = threadIdx.x;
    __shared__ float P[8 * 24 * 24];
    __shared__ float snq[192], snk[192];
    if (t < 192) {
        snq[t] = fmaxf(sqrtf(ssq[b * 384 + t]), 1e-12f);
        snk[t] = fmaxf(sqrtf(ssq[b * 384 + 192 + t]), 1e-12f);
    }
    __syncthreads();
    if (t < 192) {
        int h = t / 24, c = t % 24;
        float tmpv = temp[h];
        float dvar = resc[h] * var[b * 192 + t];
        const float* Gp = G + (size_t)(b * 8 + h) * 576 + c * 24;
        float inq = tmpv / snq[t];
        float lg[24]; float mx = -1e30f;
#pragma unroll
        for (int d = 0; d < 24; ++d) {
            float v = Gp[d] * inq / snk[h * 24 + d];
            if (d == c) v += dvar;
            lg[d] = v; mx = fmaxf(mx, v);
        }
        float sum = 0.f;
#pragma unroll
        for (int d = 0; d < 24; ++d) { float e = __expf(lg[d] - mx); lg[d] = e; sum += e; }
        float inv = 1.f / sum;
#pragma unroll
        for (int d = 0; d < 24; ++d) P[(h * 24 + c) * 24 + d] = lg[d] * inv;
    }
    __syncthreads();
#pragma unroll
    for (int i = 0; i < 6; ++i) {
        int idx = t + (blockIdx.y * 6 + i) * 256;
        int co = idx / 192, hd = idx % 192;
        int h2 = hd / 24, d = hd % 24;
        float a = 0.f;
#pragma unroll
        for (int c2 = 0; c2 < 24; ++c2)
            a += wproj[co * 192 + h2 * 24 + c2] * P[(h2 * 24 + c2) * 24 + d];
        Weff[(size_t)b * 36864 + idx] = f2b(a);
    }
}

// ---------------------------------------------------------------------------
extern "C" void kernel_launch(void* const* d_in, const int* in_sizes, int n_in,
                              void* d_out, int out_size, void* d_ws, size_t ws_size,
                              hipStream_t stream) {
    const float* x      = (const float*)d_in[0];
    const float* wdw    = (const float*)d_in[1];
    const float* wqkv   = (const float*)d_in[2];
    const float* wqkvdw = (const float*)d_in[3];
    const float* wproj  = (const float*)d_in[4];
    const float* temp   = (const float*)d_in[5];
    const float* resc   = (const float*)d_in[6];
    float* out = (float*)d_out;

    char* ws = (char*)d_ws;
    ushort_t* qkvraw = (ushort_t*)ws;                              // 150,994,944 B (bf16)
    ushort_t* qkvd   = (ushort_t*)(ws + 150994944);                // 150,994,944 B (bf16)
    char* small = ws + 301989888;
    float* var  = (float*)small;                                   // 6,144 B
    float* ssq  = (float*)(small + 6144);                          // 12,288 B
    float* G    = (float*)(small + 6144 + 12288);                  // 147,456 B
    ushort_t* Weff = (ushort_t*)(small + 6144 + 12288 + 147456);   // 589,824 B

    // xb (bf16 x, 50.3 MB) aliases qkvd start; wqb (bf16 wqkv, 221 KB) aliases
    // qkvd tail (offset 120 MB) — both dead before k_dwqkv overwrites qkvd
    ushort_t* xb  = qkvd;
    ushort_t* wqb = qkvd + 60000000;

    (void)hipMemsetAsync(G, 0, 147456, stream);
    k_cvt<<<dim3(54), dim3(256), 0, stream>>>(wqkv, wqb, 13824);
    k_dwvar<<<dim3(1536), dim3(256), 0, stream>>>(x, wdw, var, xb);
    k_gemm<0><<<dim3(128, 3, 8), dim3(256), 0, stream>>>(wqb, 0L, xb, 3145728L, qkvraw, 9437184L, 192);
    k_dwqkv<<<dim3(4608), dim3(256), 0, stream>>>(qkvraw, wqkvdw, qkvd, ssq);
    k_gram<<<dim3(8, 64), dim3(256), 0, stream>>>(qkvd, G);
    k_smweff<<<dim3(8, 24), dim3(256), 0, stream>>>(G, ssq, var, wproj, temp, resc, Weff);
    k_gemm<1><<<dim3(128, 1, 8), dim3(256), 0, stream>>>(Weff, 36864L, qkvd + (size_t)384 * HW, 9437184L, out, 3145728L, 192);
}

// Round 4
// 373.444 us; speedup vs baseline: 1.0869x; 1.0869x over previous
//
#include <hip/hip_runtime.h>
#include <hip/hip_bf16.h>

typedef unsigned short ushort_t;
typedef __bf16 bf16x8 __attribute__((ext_vector_type(8)));
typedef float f32x4 __attribute__((ext_vector_type(4)));
typedef unsigned short us8 __attribute__((ext_vector_type(8)));
typedef unsigned short us4 __attribute__((ext_vector_type(4)));

#define HW 16384
#define CDIM 192
#define QKVC 576

static __device__ __forceinline__ float b2f(unsigned short u) {
    union { unsigned int i; float f; } cv; cv.i = ((unsigned int)u) << 16; return cv.f;
}
static __device__ __forceinline__ unsigned short f2b(float f) {
    union { __bf16 h; unsigned short u; } cv; cv.h = (__bf16)f; return cv.u;
}

// ---------------------------------------------------------------------------
// K0: one-time fp32 -> bf16 convert (wqkv weights), 8 elems/thread
// ---------------------------------------------------------------------------
__global__ __launch_bounds__(256) void k_cvt(const float* __restrict__ src,
                                             ushort_t* __restrict__ dst, int n8) {
    int i = blockIdx.x * 256 + threadIdx.x;
    if (i >= n8) return;
    f32x4 a = *(const f32x4*)&src[i * 8];
    f32x4 b = *(const f32x4*)&src[i * 8 + 4];
    us8 o;
#pragma unroll
    for (int e = 0; e < 4; ++e) { o[e] = f2b(a[e]); o[4 + e] = f2b(b[e]); }
    *(us8*)&dst[i * 8] = o;
}

// ---------------------------------------------------------------------------
// K1: depthwise 3x3 (fp32) on x + unbiased variance over HxW per (b,c)
// plane staged in LDS fp32 with +4 row pad (bank spread) + zero row
// also emits bf16 copy of x (xb) for the qkv GEMM's B-panel
// ---------------------------------------------------------------------------
__global__ __launch_bounds__(256) void k_dwvar(const float* __restrict__ x,
                                               const float* __restrict__ wdw,
                                               float* __restrict__ var,
                                               ushort_t* __restrict__ xb) {
    __shared__ __align__(16) float pl[128 * 132 + 132];   // rows stride 132, zero row at 16896
    __shared__ float red[8];
    int bc = blockIdx.x;                // b*192 + c
    int c = bc % CDIM;
    const float* xp = x + (size_t)bc * HW;
    ushort_t* xbp = xb + (size_t)bc * HW;
    int t = threadIdx.x;
#pragma unroll
    for (int i = 0; i < 16; ++i) {
        int gi = t + i * 256;           // float4 index [0,4096)
        int y = gi >> 5, xq = (gi & 31) << 2;
        f32x4 v4 = *(const f32x4*)&xp[gi * 4];
        *(f32x4*)&pl[y * 132 + xq] = v4;
        us4 b4;
#pragma unroll
        for (int j = 0; j < 4; ++j) b4[j] = f2b(v4[j]);
        *(us4*)&xbp[gi * 4] = b4;
    }
    if (t < 33) { f32x4 zz = {0.f, 0.f, 0.f, 0.f}; *(f32x4*)&pl[16896 + t * 4] = zz; }
    float w[9];
#pragma unroll
    for (int j = 0; j < 9; ++j) w[j] = wdw[c * 9 + j];
    __syncthreads();

    int y = t >> 1, xs = (t & 1) * 64;
    int yb0 = (y > 0)   ? (y - 1) * 132 : 16896;
    int yb1 = y * 132;
    int yb2 = (y < 127) ? (y + 1) * 132 : 16896;
    float l0 = 0.f, l1 = 0.f, l2 = 0.f;
    if (xs != 0) { l0 = pl[yb0 + 63]; l1 = pl[yb1 + 63]; l2 = pl[yb2 + 63]; }
    float s1 = 0.f, s2 = 0.f;
#pragma unroll
    for (int g = 0; g < 8; ++g) {
        int x0 = xs + g * 8;
        float e0[10], e1[10], e2[10];
        e0[0] = l0; e1[0] = l1; e2[0] = l2;
        f32x4 a0 = *(const f32x4*)&pl[yb0 + x0], b0 = *(const f32x4*)&pl[yb0 + x0 + 4];
        f32x4 a1 = *(const f32x4*)&pl[yb1 + x0], b1 = *(const f32x4*)&pl[yb1 + x0 + 4];
        f32x4 a2 = *(const f32x4*)&pl[yb2 + x0], b2 = *(const f32x4*)&pl[yb2 + x0 + 4];
#pragma unroll
        for (int j = 0; j < 4; ++j) {
            e0[1 + j] = a0[j]; e0[5 + j] = b0[j];
            e1[1 + j] = a1[j]; e1[5 + j] = b1[j];
            e2[1 + j] = a2[j]; e2[5 + j] = b2[j];
        }
        float r0 = 0.f, r1 = 0.f, r2 = 0.f;
        if (x0 + 8 < 128) { r0 = pl[yb0 + x0 + 8]; r1 = pl[yb1 + x0 + 8]; r2 = pl[yb2 + x0 + 8]; }
        e0[9] = r0; e1[9] = r1; e2[9] = r2;
#pragma unroll
        for (int j = 0; j < 8; ++j) {
            float o = e0[j] * w[0] + e0[j + 1] * w[1] + e0[j + 2] * w[2]
                    + e1[j] * w[3] + e1[j + 1] * w[4] + e1[j + 2] * w[5]
                    + e2[j] * w[6] + e2[j + 1] * w[7] + e2[j + 2] * w[8];
            s1 += o; s2 += o * o;
        }
        l0 = e0[8]; l1 = e1[8]; l2 = e2[8];
    }
#pragma unroll
    for (int off = 32; off; off >>= 1) { s1 += __shfl_xor(s1, off); s2 += __shfl_xor(s2, off); }
    int wv = t >> 6;
    if ((t & 63) == 0) { red[wv * 2] = s1; red[wv * 2 + 1] = s2; }
    __syncthreads();
    if (t == 0) {
        float S1 = red[0] + red[2] + red[4] + red[6];
        float S2 = red[1] + red[3] + red[5] + red[7];
        var[bc] = (S2 - S1 * S1 * (1.0f / 16384.f)) * (1.0f / 16383.f);
    }
}

// ---------------------------------------------------------------------------
// K3: depthwise 3x3 on qkv planes (bf16 in/out, fp32 math/weights) + sum-sq
// LDS rows stride 136 bf16 (+8 pad) + zero row at 17408
// ---------------------------------------------------------------------------
__global__ __launch_bounds__(256) void k_dwqkv(const ushort_t* __restrict__ qkvraw,
                                               const float* __restrict__ wqd,
                                               ushort_t* __restrict__ qkvd,
                                               float* __restrict__ ssq) {
    __shared__ __align__(16) ushort_t pl[128 * 136 + 136];
    __shared__ float red[4];
    int bo = blockIdx.x;               // b*576 + o
    int o = bo % QKVC, b = bo / QKVC;
    const ushort_t* xp = qkvraw + (size_t)bo * HW;
    ushort_t* op = qkvd + (size_t)bo * HW;
    int t = threadIdx.x;
#pragma unroll
    for (int i = 0; i < 8; ++i) {
        int gi = t + i * 256;           // us8 index [0,2048)
        int y = gi >> 4, xo = (gi & 15) * 8;
        *(us8*)&pl[y * 136 + xo] = *(const us8*)&xp[gi * 8];
    }
    if (t < 17) { us8 zz = {}; *(us8*)&pl[17408 + t * 8] = zz; }
    float w[9];
#pragma unroll
    for (int j = 0; j < 9; ++j) w[j] = wqd[o * 9 + j];
    __syncthreads();

    int y = t >> 1, xs = (t & 1) * 64;
    int yb0 = (y > 0)   ? (y - 1) * 136 : 17408;
    int yb1 = y * 136;
    int yb2 = (y < 127) ? (y + 1) * 136 : 17408;
    float l0 = 0.f, l1 = 0.f, l2 = 0.f;
    if (xs != 0) { l0 = b2f(pl[yb0 + 63]); l1 = b2f(pl[yb1 + 63]); l2 = b2f(pl[yb2 + 63]); }
    float s2 = 0.f;
#pragma unroll
    for (int g = 0; g < 8; ++g) {
        int x0 = xs + g * 8;
        us8 v0 = *(const us8*)&pl[yb0 + x0];
        us8 v1 = *(const us8*)&pl[yb1 + x0];
        us8 v2 = *(const us8*)&pl[yb2 + x0];
        float r0 = 0.f, r1 = 0.f, r2 = 0.f;
        if (x0 + 8 < 128) { r0 = b2f(pl[yb0 + x0 + 8]); r1 = b2f(pl[yb1 + x0 + 8]); r2 = b2f(pl[yb2 + x0 + 8]); }
        float e0[10], e1[10], e2[10];
        e0[0] = l0; e1[0] = l1; e2[0] = l2;
#pragma unroll
        for (int j = 0; j < 8; ++j) { e0[j + 1] = b2f(v0[j]); e1[j + 1] = b2f(v1[j]); e2[j + 1] = b2f(v2[j]); }
        e0[9] = r0; e1[9] = r1; e2[9] = r2;
        us8 ob;
#pragma unroll
        for (int j = 0; j < 8; ++j) {
            float ov = e0[j] * w[0] + e0[j + 1] * w[1] + e0[j + 2] * w[2]
                     + e1[j] * w[3] + e1[j + 1] * w[4] + e1[j + 2] * w[5]
                     + e2[j] * w[6] + e2[j + 1] * w[7] + e2[j + 2] * w[8];
            unsigned short bits = f2b(ov);
            ob[j] = bits;
            float rv = b2f(bits);
            s2 += rv * rv;
        }
        *(us8*)&op[(size_t)y * 128 + x0] = ob;
        l0 = e0[8]; l1 = e1[8]; l2 = e2[8];
    }
    if (o < 2 * CDIM) {
#pragma unroll
        for (int off = 32; off; off >>= 1) s2 += __shfl_xor(s2, off);
        int wv = t >> 6;
        if ((t & 63) == 0) red[wv] = s2;
        __syncthreads();
        if (t == 0) ssq[b * 384 + o] = red[0] + red[1] + red[2] + red[3];
    }
}

// ---------------------------------------------------------------------------
// GEMM: C[b] = A[b] (MxK bf16, row-major) * B[b] (KxN bf16, N contiguous)
// BM=192 BN=128 BK=64; 4 waves x 3 row-tiles x 8 col-tiles; 16x16x32 bf16
// As: row-XOR swizzle. Bs: granule swizzle (verified conflict-free, R3 PMC=0)
// NEW: B register-prefetch (load k+1 under MFMA of k) + LDS-staged coalesced
// C epilogue (12 us8 / 24 f32x4 vector stores instead of 96 scalar)
// ---------------------------------------------------------------------------
template<int CF>
__global__ __launch_bounds__(256) void k_gemm(const ushort_t* __restrict__ Av, long sAb,
                                              const ushort_t* __restrict__ Bv, long sBb,
                                              void* __restrict__ Cv, long sCb, int K) {
    __shared__ __align__(16) char smem[49152];
    ushort_t* As = (ushort_t*)smem;                 // [192][64] bf16, row-XOR swizzled
    ushort_t* Bs = (ushort_t*)(smem + 24576);       // [128][64] bf16, granule swizzled
    int t = threadIdx.x;
    int wv = t >> 6, lane = t & 63, quad = lane >> 4, l15 = lane & 15;
    size_t aoff = (size_t)blockIdx.z * sAb + (size_t)blockIdx.y * 192 * K;
    size_t boff = (size_t)blockIdx.z * sBb + (size_t)blockIdx.x * 128;
    size_t coff = (size_t)blockIdx.z * sCb + (size_t)blockIdx.y * 192 * HW + (size_t)blockIdx.x * 128;
    f32x4 acc[24] = {};
    int bkr = t >> 3, bn0 = (t & 7) * 16, tlow = t & 7;
    int gk0 = bkr >> 3, klo = bkr & 7;
    const ushort_t* Bp = Bv + boff;
    // prefetch iteration 0's B rows into registers
    us8 pb0 = *(const us8*)&Bp[(size_t)bkr * HW + bn0];
    us8 pb1 = *(const us8*)&Bp[(size_t)bkr * HW + bn0 + 8];
    us8 pb2 = *(const us8*)&Bp[(size_t)(bkr + 32) * HW + bn0];
    us8 pb3 = *(const us8*)&Bp[(size_t)(bkr + 32) * HW + bn0 + 8];
    int nIter = K >> 6;
    for (int it = 0; it < nIter; ++it) {
        int kk = it << 6;
        // --- A stage: 192 rows x 64 k, 6 us8 slots per thread, row-XOR swizzle ---
#pragma unroll
        for (int i = 0; i < 6; ++i) {
            int s = t + i * 256;                   // [0,1536)
            int row = s >> 3, kc = (s & 7) * 8;
            int kcs = kc ^ ((row & 7) * 8);
            *(uint4*)&As[row * 64 + kcs] = *(const uint4*)&Av[aoff + (size_t)row * K + kk + kc];
        }
        // --- B stage from prefetched regs, granule swizzle (same mapping as R3) ---
#pragma unroll
        for (int e = 0; e < 8; ++e) {
            int col0 = ((gk0 ^ tlow ^ e) << 3) + klo;
            Bs[(bn0 + e) * 64 + col0] = pb0[e];
            Bs[(bn0 + 8 + e) * 64 + col0] = pb1[e];
            int col1 = (((gk0 + 4) ^ tlow ^ e) << 3) + klo;
            Bs[(bn0 + e) * 64 + col1] = pb2[e];
            Bs[(bn0 + 8 + e) * 64 + col1] = pb3[e];
        }
        __syncthreads();
        // --- issue next iteration's B loads: fly under the MFMA phase ---
        if (it + 1 < nIter) {
            const ushort_t* Bn = &Bp[(size_t)(kk + 64) * HW];
            pb0 = *(const us8*)&Bn[(size_t)bkr * HW + bn0];
            pb1 = *(const us8*)&Bn[(size_t)bkr * HW + bn0 + 8];
            pb2 = *(const us8*)&Bn[(size_t)(bkr + 32) * HW + bn0];
            pb3 = *(const us8*)&Bn[(size_t)(bkr + 32) * HW + bn0 + 8];
        }
        // --- MFMA phase (unchanged, conflict-free per R3 PMC) ---
#pragma unroll
        for (int s = 0; s < 2; ++s) {
            int r0 = wv * 16 + l15, r1 = 64 + r0, r2 = 128 + r0;
            int ko = s * 32 + quad * 8;
            bf16x8 af0 = *(const bf16x8*)&As[r0 * 64 + (ko ^ ((r0 & 7) * 8))];
            bf16x8 af1 = *(const bf16x8*)&As[r1 * 64 + (ko ^ ((r1 & 7) * 8))];
            bf16x8 af2 = *(const bf16x8*)&As[r2 * 64 + (ko ^ ((r2 & 7) * 8))];
#pragma unroll
            for (int tc = 0; tc < 8; ++tc) {
                int n = tc * 16 + l15;
                int g = (s * 4 + quad) ^ ((tc ^ l15) & 7);
                bf16x8 bfr = *(const bf16x8*)&Bs[n * 64 + (g << 3)];
                acc[tc]      = __builtin_amdgcn_mfma_f32_16x16x32_bf16(af0, bfr, acc[tc],      0, 0, 0);
                acc[8 + tc]  = __builtin_amdgcn_mfma_f32_16x16x32_bf16(af1, bfr, acc[8 + tc],  0, 0, 0);
                acc[16 + tc] = __builtin_amdgcn_mfma_f32_16x16x32_bf16(af2, bfr, acc[16 + tc], 0, 0, 0);
            }
        }
        __syncthreads();
    }
    // --- epilogue: stage C in LDS, vector-store coalesced ---
    if (CF == 0) {
        ushort_t* Ct = (ushort_t*)smem;            // 192*128*2 = 49152
#pragma unroll
        for (int rt = 0; rt < 3; ++rt)
#pragma unroll
            for (int tc = 0; tc < 8; ++tc)
#pragma unroll
                for (int r = 0; r < 4; ++r)
                    Ct[(rt * 64 + wv * 16 + quad * 4 + r) * 128 + tc * 16 + l15] = f2b(acc[rt * 8 + tc][r]);
        __syncthreads();
        ushort_t* Co = (ushort_t*)Cv;
#pragma unroll
        for (int i = 0; i < 12; ++i) {
            int s = t + i * 256;                   // [0,3072)
            int row = s >> 4, c8 = (s & 15) * 8;
            *(us8*)&Co[coff + (size_t)row * HW + c8] = *(us8*)&Ct[row * 128 + c8];
        }
    } else {
        float* Cf = (float*)smem;                  // 64*128*4 = 32768 per pass
        float* Co = (float*)Cv;
#pragma unroll
        for (int rt = 0; rt < 3; ++rt) {
            if (rt) __syncthreads();
#pragma unroll
            for (int tc = 0; tc < 8; ++tc)
#pragma unroll
                for (int r = 0; r < 4; ++r)
                    Cf[(wv * 16 + quad * 4 + r) * 128 + tc * 16 + l15] = acc[rt * 8 + tc][r];
            __syncthreads();
#pragma unroll
            for (int i = 0; i < 8; ++i) {
                int s = t + i * 256;               // [0,2048)
                int row = s >> 5, c4 = (s & 31) * 4;
                *(f32x4*)&Co[coff + (size_t)(rt * 64 + row) * HW + c4] = *(f32x4*)&Cf[row * 128 + c4];
            }
        }
    }
}

// ---------------------------------------------------------------------------
// K4: Gram G[b,h] = q . k^T (24x24, K=16384), LDS-staged, mfma, atomic combine
// ---------------------------------------------------------------------------
__global__ __launch_bounds__(256) void k_gram(const ushort_t* __restrict__ qkvd,
                                              float* __restrict__ G) {
    __shared__ __align__(16) ushort_t qs[24 * 264];
    __shared__ __align__(16) ushort_t ks[24 * 264];
    int bh = blockIdx.y;
    int b = bh >> 3, h = bh & 7;
    int t = threadIdx.x, wv = t >> 6, lane = t & 63, quad = lane >> 4, l15 = lane & 15;
    const ushort_t* qb = qkvd + (size_t)b * 9437184 + (size_t)(h * 24) * HW;
    const ushort_t* kp = qb + (size_t)CDIM * HW;
    f32x4 a00 = {}, a01 = {}, a10 = {}, a11 = {};
    bf16x8 z = {};
    bool hi = (l15 < 8);
    int kbase0 = blockIdx.x * 2048;
    for (int sub = 0; sub < 8; ++sub) {
        int kbase = kbase0 + sub * 256;
#pragma unroll
        for (int j = 0; j < 3; ++j) {
            int gi = t + j * 256;       // [0,768)
            int row = gi >> 5, c8 = (gi & 31) * 8;
            *(us8*)&qs[row * 264 + c8] = *(const us8*)&qb[(size_t)row * HW + kbase + c8];
            *(us8*)&ks[row * 264 + c8] = *(const us8*)&kp[(size_t)row * HW + kbase + c8];
        }
        __syncthreads();
#pragma unroll
        for (int s = 0; s < 2; ++s) {
            int ko = (wv * 2 + s) * 32 + quad * 8;
            bf16x8 qa0 = *(const bf16x8*)&qs[l15 * 264 + ko];
            bf16x8 qa1 = hi ? *(const bf16x8*)&qs[(16 + l15) * 264 + ko] : z;
            bf16x8 kb0 = *(const bf16x8*)&ks[l15 * 264 + ko];
            bf16x8 kb1 = hi ? *(const bf16x8*)&ks[(16 + l15) * 264 + ko] : z;
            a00 = __builtin_amdgcn_mfma_f32_16x16x32_bf16(qa0, kb0, a00, 0, 0, 0);
            a01 = __builtin_amdgcn_mfma_f32_16x16x32_bf16(qa0, kb1, a01, 0, 0, 0);
            a10 = __builtin_amdgcn_mfma_f32_16x16x32_bf16(qa1, kb0, a10, 0, 0, 0);
            a11 = __builtin_amdgcn_mfma_f32_16x16x32_bf16(qa1, kb1, a11, 0, 0, 0);
        }
        __syncthreads();
    }
    float* Gp = G + (size_t)bh * 576;
#pragma unroll
    for (int r = 0; r < 4; ++r) {
        int r0 = quad * 4 + r, r1 = 16 + quad * 4 + r;
        int c0 = l15, c1 = 16 + l15;
        atomicAdd(&Gp[r0 * 24 + c0], a00[r]);
        if (c1 < 24) atomicAdd(&Gp[r0 * 24 + c1], a01[r]);
        if (r1 < 24) atomicAdd(&Gp[r1 * 24 + c0], a10[r]);
        if (r1 < 24 && c1 < 24) atomicAdd(&Gp[r1 * 24 + c1], a11[r]);
    }
}

// ---------------------------------------------------------------------------
// K5: softmax(P) per (b,h) and Weff[b] = W_proj * blockdiag(P)  (Weff bf16)
// grid (8, 24): each block redoes the cheap softmax, emits 1/24 of Weff
// ---------------------------------------------------------------------------
__global__ __launch_bounds__(256) void k_smweff(const float* __restrict__ G,
                                                const float* __restrict__ ssq,
                                                const float* __restrict__ var,
                                                const float* __restrict__ wproj,
                                                const float* __restrict__ temp,
                                                const float* __restrict__ resc,
                                                ushort_t* __restrict__ Weff) {
    int b = blockIdx.x, t = threadIdx.x;
    __shared__ float P[8 * 24 * 24];
    __shared__ float snq[192], snk[192];
    if (t < 192) {
        snq[t] = fmaxf(sqrtf(ssq[b * 384 + t]), 1e-12f);
        snk[t] = fmaxf(sqrtf(ssq[b * 384 + 192 + t]), 1e-12f);
    }
    __syncthreads();
    if (t < 192) {
        int h = t / 24, c = t % 24;
        float tmpv = temp[h];
        float dvar = resc[h] * var[b * 192 + t];
        const float* Gp = G + (size_t)(b * 8 + h) * 576 + c * 24;
        float inq = tmpv / snq[t];
        float lg[24]; float mx = -1e30f;
#pragma unroll
        for (int d = 0; d < 24; ++d) {
            float v = Gp[d] * inq / snk[h * 24 + d];
            if (d == c) v += dvar;
            lg[d] = v; mx = fmaxf(mx, v);
        }
        float sum = 0.f;
#pragma unroll
        for (int d = 0; d < 24; ++d) { float e = __expf(lg[d] - mx); lg[d] = e; sum += e; }
        float inv = 1.f / sum;
#pragma unroll
        for (int d = 0; d < 24; ++d) P[(h * 24 + c) * 24 + d] = lg[d] * inv;
    }
    __syncthreads();
#pragma unroll
    for (int i = 0; i < 6; ++i) {
        int idx = t + (blockIdx.y * 6 + i) * 256;
        int co = idx / 192, hd = idx % 192;
        int h2 = hd / 24, d = hd % 24;
        float a = 0.f;
#pragma unroll
        for (int c2 = 0; c2 < 24; ++c2)
            a += wproj[co * 192 + h2 * 24 + c2] * P[(h2 * 24 + c2) * 24 + d];
        Weff[(size_t)b * 36864 + idx] = f2b(a);
    }
}

// ---------------------------------------------------------------------------
extern "C" void kernel_launch(void* const* d_in, const int* in_sizes, int n_in,
                              void* d_out, int out_size, void* d_ws, size_t ws_size,
                              hipStream_t stream) {
    const float* x      = (const float*)d_in[0];
    const float* wdw    = (const float*)d_in[1];
    const float* wqkv   = (const float*)d_in[2];
    const float* wqkvdw = (const float*)d_in[3];
    const float* wproj  = (const float*)d_in[4];
    const float* temp   = (const float*)d_in[5];
    const float* resc   = (const float*)d_in[6];
    float* out = (float*)d_out;

    char* ws = (char*)d_ws;
    ushort_t* qkvraw = (ushort_t*)ws;                              // 150,994,944 B (bf16)
    ushort_t* qkvd   = (ushort_t*)(ws + 150994944);                // 150,994,944 B (bf16)
    char* small = ws + 301989888;
    float* var  = (float*)small;                                   // 6,144 B
    float* ssq  = (float*)(small + 6144);                          // 12,288 B
    float* G    = (float*)(small + 6144 + 12288);                  // 147,456 B
    ushort_t* Weff = (ushort_t*)(small + 6144 + 12288 + 147456);   // 589,824 B

    // xb (bf16 x, 50.3 MB) aliases qkvd start; wqb (bf16 wqkv, 221 KB) aliases
    // qkvd tail (offset 120 MB) — both dead before k_dwqkv overwrites qkvd
    ushort_t* xb  = qkvd;
    ushort_t* wqb = qkvd + 60000000;

    (void)hipMemsetAsync(G, 0, 147456, stream);
    k_cvt<<<dim3(54), dim3(256), 0, stream>>>(wqkv, wqb, 13824);
    k_dwvar<<<dim3(1536), dim3(256), 0, stream>>>(x, wdw, var, xb);
    k_gemm<0><<<dim3(128, 3, 8), dim3(256), 0, stream>>>(wqb, 0L, xb, 3145728L, qkvraw, 9437184L, 192);
    k_dwqkv<<<dim3(4608), dim3(256), 0, stream>>>(qkvraw, wqkvdw, qkvd, ssq);
    k_gram<<<dim3(8, 64), dim3(256), 0, stream>>>(qkvd, G);
    k_smweff<<<dim3(8, 24), dim3(256), 0, stream>>>(G, ssq, var, wproj, temp, resc, Weff);
    k_gemm<1><<<dim3(128, 1, 8), dim3(256), 0, stream>>>(Weff, 36864L, qkvd + (size_t)384 * HW, 9437184L, out, 3145728L, 192);
}

// Round 6
// 365.080 us; speedup vs baseline: 1.1118x; 1.0229x over previous
//
#include <hip/hip_runtime.h>
#include <hip/hip_bf16.h>

typedef unsigned short ushort_t;
typedef __bf16 bf16x8 __attribute__((ext_vector_type(8)));
typedef float f32x4 __attribute__((ext_vector_type(4)));
typedef unsigned short us8 __attribute__((ext_vector_type(8)));
typedef unsigned short us4 __attribute__((ext_vector_type(4)));

#define HW 16384
#define CDIM 192
#define QKVC 576

static __device__ __forceinline__ float b2f(unsigned short u) {
    union { unsigned int i; float f; } cv; cv.i = ((unsigned int)u) << 16; return cv.f;
}
static __device__ __forceinline__ unsigned short f2b(float f) {
    union { __bf16 h; unsigned short u; } cv; cv.h = (__bf16)f; return cv.u;
}

// ---------------------------------------------------------------------------
// K0: one-time fp32 -> bf16 convert (wqkv weights), 8 elems/thread
// ---------------------------------------------------------------------------
__global__ __launch_bounds__(256) void k_cvt(const float* __restrict__ src,
                                             ushort_t* __restrict__ dst, int n8) {
    int i = blockIdx.x * 256 + threadIdx.x;
    if (i >= n8) return;
    f32x4 a = *(const f32x4*)&src[i * 8];
    f32x4 b = *(const f32x4*)&src[i * 8 + 4];
    us8 o;
#pragma unroll
    for (int e = 0; e < 4; ++e) { o[e] = f2b(a[e]); o[4 + e] = f2b(b[e]); }
    *(us8*)&dst[i * 8] = o;
}

// ---------------------------------------------------------------------------
// K1: depthwise 3x3 (fp32) on x, HALF-plane per block (64 rows + 2 halo)
// partial sums (S1,S2) atomically combined; also emits bf16 copy of x (xb)
// one-row-per-lane mapping: b128 reads at the 8-dword/bank LDS floor
// ---------------------------------------------------------------------------
__global__ __launch_bounds__(256) void k_dwvar(const float* __restrict__ x,
                                               const float* __restrict__ wdw,
                                               float* __restrict__ vs1,
                                               float* __restrict__ vs2,
                                               ushort_t* __restrict__ xb) {
    __shared__ __align__(16) float pl[66 * 132];    // LDS row i = plane row rb+i-1
    __shared__ float red[8];
    int blk = blockIdx.x;
    int bc = blk >> 1, half = blk & 1, rb = half * 64;
    int c = bc % CDIM;
    const float* xp = x + (size_t)bc * HW;
    ushort_t* xbp = xb + (size_t)bc * HW;
    int t = threadIdx.x;
#pragma unroll
    for (int i = 0; i < 8; ++i) {
        int gi = t + i * 256;            // f32x4 granule [0,2048)
        int row = gi >> 5, q4 = (gi & 31) * 4;
        f32x4 v4 = *(const f32x4*)&xp[(size_t)(rb + row) * 128 + q4];
        *(f32x4*)&pl[(row + 1) * 132 + q4] = v4;
        us4 b4;
#pragma unroll
        for (int j = 0; j < 4; ++j) b4[j] = f2b(v4[j]);
        *(us4*)&xbp[(size_t)(rb + row) * 128 + q4] = b4;
    }
    if (t < 32) {                        // top halo (plane row rb-1 or zeros)
        f32x4 v = {0.f, 0.f, 0.f, 0.f};
        if (rb > 0) v = *(const f32x4*)&xp[(size_t)(rb - 1) * 128 + t * 4];
        *(f32x4*)&pl[t * 4] = v;
    } else if (t < 64) {                 // bottom halo (plane row rb+64 or zeros)
        int g = t - 32;
        f32x4 v = {0.f, 0.f, 0.f, 0.f};
        if (rb + 64 < 128) v = *(const f32x4*)&xp[(size_t)(rb + 64) * 128 + g * 4];
        *(f32x4*)&pl[65 * 132 + g * 4] = v;
    }
    float w[9];
#pragma unroll
    for (int j = 0; j < 9; ++j) w[j] = wdw[c * 9 + j];
    __syncthreads();

    int lane = t & 63, wv = t >> 6;
    int y = lane, xs = wv * 32;          // output row rb+y, cols [xs, xs+32)
    int yb0 = y * 132, yb1 = yb0 + 132, yb2 = yb1 + 132;
    float l0 = 0.f, l1 = 0.f, l2 = 0.f;
    if (xs != 0) { l0 = pl[yb0 + xs - 1]; l1 = pl[yb1 + xs - 1]; l2 = pl[yb2 + xs - 1]; }
    float s1 = 0.f, s2 = 0.f;
#pragma unroll
    for (int g = 0; g < 4; ++g) {
        int x0 = xs + g * 8;
        float e0[10], e1[10], e2[10];
        e0[0] = l0; e1[0] = l1; e2[0] = l2;
        f32x4 a0 = *(const f32x4*)&pl[yb0 + x0], b0 = *(const f32x4*)&pl[yb0 + x0 + 4];
        f32x4 a1 = *(const f32x4*)&pl[yb1 + x0], b1 = *(const f32x4*)&pl[yb1 + x0 + 4];
        f32x4 a2 = *(const f32x4*)&pl[yb2 + x0], b2 = *(const f32x4*)&pl[yb2 + x0 + 4];
#pragma unroll
        for (int j = 0; j < 4; ++j) {
            e0[1 + j] = a0[j]; e0[5 + j] = b0[j];
            e1[1 + j] = a1[j]; e1[5 + j] = b1[j];
            e2[1 + j] = a2[j]; e2[5 + j] = b2[j];
        }
        float r0v = 0.f, r1v = 0.f, r2v = 0.f;
        if (x0 + 8 < 128) { r0v = pl[yb0 + x0 + 8]; r1v = pl[yb1 + x0 + 8]; r2v = pl[yb2 + x0 + 8]; }
        e0[9] = r0v; e1[9] = r1v; e2[9] = r2v;
#pragma unroll
        for (int j = 0; j < 8; ++j) {
            float o = e0[j] * w[0] + e0[j + 1] * w[1] + e0[j + 2] * w[2]
                    + e1[j] * w[3] + e1[j + 1] * w[4] + e1[j + 2] * w[5]
                    + e2[j] * w[6] + e2[j + 1] * w[7] + e2[j + 2] * w[8];
            s1 += o; s2 += o * o;
        }
        l0 = e0[8]; l1 = e1[8]; l2 = e2[8];
    }
#pragma unroll
    for (int off = 32; off; off >>= 1) { s1 += __shfl_xor(s1, off); s2 += __shfl_xor(s2, off); }
    if (lane == 0) { red[wv * 2] = s1; red[wv * 2 + 1] = s2; }
    __syncthreads();
    if (t == 0) {
        atomicAdd(&vs1[bc], red[0] + red[2] + red[4] + red[6]);
        atomicAdd(&vs2[bc], red[1] + red[3] + red[5] + red[7]);
    }
}

// ---------------------------------------------------------------------------
// K3: depthwise 3x3 on qkv planes, HALF-plane per block (64 rows + 2 halo)
// bf16 in/out, fp32 math; ssq partial atomically combined
// LDS 66 x 136 bf16 (17.9 KB -> 8 blocks/CU); one-row-per-lane mapping
// ---------------------------------------------------------------------------
__global__ __launch_bounds__(256) void k_dwqkv(const ushort_t* __restrict__ qkvraw,
                                               const float* __restrict__ wqd,
                                               ushort_t* __restrict__ qkvd,
                                               float* __restrict__ ssq) {
    __shared__ __align__(16) ushort_t pl[66 * 136];
    __shared__ float red[4];
    int blk = blockIdx.x;
    int bo = blk >> 1, half = blk & 1, rb = half * 64;
    int o = bo % QKVC, b = bo / QKVC;
    const ushort_t* xp = qkvraw + (size_t)bo * HW;
    ushort_t* op = qkvd + (size_t)bo * HW;
    int t = threadIdx.x;
#pragma unroll
    for (int i = 0; i < 4; ++i) {
        int gi = t + i * 256;            // us8 granule [0,1024)
        int row = gi >> 4, gr = (gi & 15) * 8;
        *(us8*)&pl[(row + 1) * 136 + gr] = *(const us8*)&xp[(size_t)(rb + row) * 128 + gr];
    }
    if (t < 16) {                        // top halo
        us8 v = {};
        if (rb > 0) v = *(const us8*)&xp[(size_t)(rb - 1) * 128 + t * 8];
        *(us8*)&pl[t * 8] = v;
    } else if (t < 32) {                 // bottom halo
        int g = t - 16;
        us8 v = {};
        if (rb + 64 < 128) v = *(const us8*)&xp[(size_t)(rb + 64) * 128 + g * 8];
        *(us8*)&pl[65 * 136 + g * 8] = v;
    }
    float w[9];
#pragma unroll
    for (int j = 0; j < 9; ++j) w[j] = wqd[o * 9 + j];
    __syncthreads();

    int lane = t & 63, wv = t >> 6;
    int y = lane, xs = wv * 32;
    int yb0 = y * 136, yb1 = yb0 + 136, yb2 = yb1 + 136;
    float l0 = 0.f, l1 = 0.f, l2 = 0.f;
    if (xs != 0) { l0 = b2f(pl[yb0 + xs - 1]); l1 = b2f(pl[yb1 + xs - 1]); l2 = b2f(pl[yb2 + xs - 1]); }
    float s2 = 0.f;
#pragma unroll
    for (int g = 0; g < 4; ++g) {
        int x0 = xs + g * 8;
        us8 v0 = *(const us8*)&pl[yb0 + x0];
        us8 v1 = *(const us8*)&pl[yb1 + x0];
        us8 v2 = *(const us8*)&pl[yb2 + x0];
        float r0v = 0.f, r1v = 0.f, r2v = 0.f;
        if (x0 + 8 < 128) { r0v = b2f(pl[yb0 + x0 + 8]); r1v = b2f(pl[yb1 + x0 + 8]); r2v = b2f(pl[yb2 + x0 + 8]); }
        float e0[10], e1[10], e2[10];
        e0[0] = l0; e1[0] = l1; e2[0] = l2;
#pragma unroll
        for (int j = 0; j < 8; ++j) { e0[j + 1] = b2f(v0[j]); e1[j + 1] = b2f(v1[j]); e2[j + 1] = b2f(v2[j]); }
        e0[9] = r0v; e1[9] = r1v; e2[9] = r2v;
        us8 ob;
#pragma unroll
        for (int j = 0; j < 8; ++j) {
            float ov = e0[j] * w[0] + e0[j + 1] * w[1] + e0[j + 2] * w[2]
                     + e1[j] * w[3] + e1[j + 1] * w[4] + e1[j + 2] * w[5]
                     + e2[j] * w[6] + e2[j + 1] * w[7] + e2[j + 2] * w[8];
            unsigned short bits = f2b(ov);
            ob[j] = bits;
            float rv = b2f(bits);
            s2 += rv * rv;
        }
        *(us8*)&op[(size_t)(rb + y) * 128 + x0] = ob;
        l0 = e0[8]; l1 = e1[8]; l2 = e2[8];
    }
#pragma unroll
    for (int off = 32; off; off >>= 1) s2 += __shfl_xor(s2, off);
    if (lane == 0) red[wv] = s2;
    __syncthreads();
    if (t == 0 && o < 2 * CDIM)
        atomicAdd(&ssq[b * 384 + o], red[0] + red[1] + red[2] + red[3]);
}

// ---------------------------------------------------------------------------
// GEMM: C[b] = A[b] (MxK bf16, row-major) * B[b] (KxN bf16, N contiguous)
// BM=192 BN=128 BK=64; 4 waves x 3 row-tiles x 8 col-tiles; 16x16x32 bf16
// As: row-XOR swizzle. Bs: granule swizzle (verified conflict-free, R3 PMC=0)
// B register-prefetch (k+1 under MFMA of k) + LDS-staged coalesced C epilogue
// ---------------------------------------------------------------------------
template<int CF>
__global__ __launch_bounds__(256) void k_gemm(const ushort_t* __restrict__ Av, long sAb,
                                              const ushort_t* __restrict__ Bv, long sBb,
                                              void* __restrict__ Cv, long sCb, int K) {
    __shared__ __align__(16) char smem[49152];
    ushort_t* As = (ushort_t*)smem;                 // [192][64] bf16, row-XOR swizzled
    ushort_t* Bs = (ushort_t*)(smem + 24576);       // [128][64] bf16, granule swizzled
    int t = threadIdx.x;
    int wv = t >> 6, lane = t & 63, quad = lane >> 4, l15 = lane & 15;
    size_t aoff = (size_t)blockIdx.z * sAb + (size_t)blockIdx.y * 192 * K;
    size_t boff = (size_t)blockIdx.z * sBb + (size_t)blockIdx.x * 128;
    size_t coff = (size_t)blockIdx.z * sCb + (size_t)blockIdx.y * 192 * HW + (size_t)blockIdx.x * 128;
    f32x4 acc[24] = {};
    int bkr = t >> 3, bn0 = (t & 7) * 16, tlow = t & 7;
    int gk0 = bkr >> 3, klo = bkr & 7;
    const ushort_t* Bp = Bv + boff;
    us8 pb0 = *(const us8*)&Bp[(size_t)bkr * HW + bn0];
    us8 pb1 = *(const us8*)&Bp[(size_t)bkr * HW + bn0 + 8];
    us8 pb2 = *(const us8*)&Bp[(size_t)(bkr + 32) * HW + bn0];
    us8 pb3 = *(const us8*)&Bp[(size_t)(bkr + 32) * HW + bn0 + 8];
    int nIter = K >> 6;
    for (int it = 0; it < nIter; ++it) {
        int kk = it << 6;
#pragma unroll
        for (int i = 0; i < 6; ++i) {
            int s = t + i * 256;                   // [0,1536)
            int row = s >> 3, kc = (s & 7) * 8;
            int kcs = kc ^ ((row & 7) * 8);
            *(uint4*)&As[row * 64 + kcs] = *(const uint4*)&Av[aoff + (size_t)row * K + kk + kc];
        }
#pragma unroll
        for (int e = 0; e < 8; ++e) {
            int col0 = ((gk0 ^ tlow ^ e) << 3) + klo;
            Bs[(bn0 + e) * 64 + col0] = pb0[e];
            Bs[(bn0 + 8 + e) * 64 + col0] = pb1[e];
            int col1 = (((gk0 + 4) ^ tlow ^ e) << 3) + klo;
            Bs[(bn0 + e) * 64 + col1] = pb2[e];
            Bs[(bn0 + 8 + e) * 64 + col1] = pb3[e];
        }
        __syncthreads();
        if (it + 1 < nIter) {
            const ushort_t* Bn = &Bp[(size_t)(kk + 64) * HW];
            pb0 = *(const us8*)&Bn[(size_t)bkr * HW + bn0];
            pb1 = *(const us8*)&Bn[(size_t)bkr * HW + bn0 + 8];
            pb2 = *(const us8*)&Bn[(size_t)(bkr + 32) * HW + bn0];
            pb3 = *(const us8*)&Bn[(size_t)(bkr + 32) * HW + bn0 + 8];
        }
#pragma unroll
        for (int s = 0; s < 2; ++s) {
            int r0 = wv * 16 + l15, r1 = 64 + r0, r2 = 128 + r0;
            int ko = s * 32 + quad * 8;
            bf16x8 af0 = *(const bf16x8*)&As[r0 * 64 + (ko ^ ((r0 & 7) * 8))];
            bf16x8 af1 = *(const bf16x8*)&As[r1 * 64 + (ko ^ ((r1 & 7) * 8))];
            bf16x8 af2 = *(const bf16x8*)&As[r2 * 64 + (ko ^ ((r2 & 7) * 8))];
#pragma unroll
            for (int tc = 0; tc < 8; ++tc) {
                int n = tc * 16 + l15;
                int g = (s * 4 + quad) ^ ((tc ^ l15) & 7);
                bf16x8 bfr = *(const bf16x8*)&Bs[n * 64 + (g << 3)];
                acc[tc]      = __builtin_amdgcn_mfma_f32_16x16x32_bf16(af0, bfr, acc[tc],      0, 0, 0);
                acc[8 + tc]  = __builtin_amdgcn_mfma_f32_16x16x32_bf16(af1, bfr, acc[8 + tc],  0, 0, 0);
                acc[16 + tc] = __builtin_amdgcn_mfma_f32_16x16x32_bf16(af2, bfr, acc[16 + tc], 0, 0, 0);
            }
        }
        __syncthreads();
    }
    if (CF == 0) {
        ushort_t* Ct = (ushort_t*)smem;            // 192*128*2 = 49152
#pragma unroll
        for (int rt = 0; rt < 3; ++rt)
#pragma unroll
            for (int tc = 0; tc < 8; ++tc)
#pragma unroll
                for (int r = 0; r < 4; ++r)
                    Ct[(rt * 64 + wv * 16 + quad * 4 + r) * 128 + tc * 16 + l15] = f2b(acc[rt * 8 + tc][r]);
        __syncthreads();
        ushort_t* Co = (ushort_t*)Cv;
#pragma unroll
        for (int i = 0; i < 12; ++i) {
            int s = t + i * 256;                   // [0,3072)
            int row = s >> 4, c8 = (s & 15) * 8;
            *(us8*)&Co[coff + (size_t)row * HW + c8] = *(us8*)&Ct[row * 128 + c8];
        }
    } else {
        float* Cf = (float*)smem;                  // 64*128*4 = 32768 per pass
        float* Co = (float*)Cv;
#pragma unroll
        for (int rt = 0; rt < 3; ++rt) {
            if (rt) __syncthreads();
#pragma unroll
            for (int tc = 0; tc < 8; ++tc)
#pragma unroll
                for (int r = 0; r < 4; ++r)
                    Cf[(wv * 16 + quad * 4 + r) * 128 + tc * 16 + l15] = acc[rt * 8 + tc][r];
            __syncthreads();
#pragma unroll
            for (int i = 0; i < 8; ++i) {
                int s = t + i * 256;               // [0,2048)
                int row = s >> 5, c4 = (s & 31) * 4;
                *(f32x4*)&Co[coff + (size_t)(rt * 64 + row) * HW + c4] = *(f32x4*)&Cf[row * 128 + c4];
            }
        }
    }
}

// ---------------------------------------------------------------------------
// K4: Gram G[b,h] = q . k^T (24x24, K=16384), LDS-staged, mfma, atomic combine
// ---------------------------------------------------------------------------
__global__ __launch_bounds__(256) void k_gram(const ushort_t* __restrict__ qkvd,
                                              float* __restrict__ G) {
    __shared__ __align__(16) ushort_t qs[24 * 264];
    __shared__ __align__(16) ushort_t ks[24 * 264];
    int bh = blockIdx.y;
    int b = bh >> 3, h = bh & 7;
    int t = threadIdx.x, wv = t >> 6, lane = t & 63, quad = lane >> 4, l15 = lane & 15;
    const ushort_t* qb = qkvd + (size_t)b * 9437184 + (size_t)(h * 24) * HW;
    const ushort_t* kp = qb + (size_t)CDIM * HW;
    f32x4 a00 = {}, a01 = {}, a10 = {}, a11 = {};
    bf16x8 z = {};
    bool hi = (l15 < 8);
    int kbase0 = blockIdx.x * 2048;
    for (int sub = 0; sub < 8; ++sub) {
        int kbase = kbase0 + sub * 256;
#pragma unroll
        for (int j = 0; j < 3; ++j) {
            int gi = t + j * 256;       // [0,768)
            int row = gi >> 5, c8 = (gi & 31) * 8;
            *(us8*)&qs[row * 264 + c8] = *(const us8*)&qb[(size_t)row * HW + kbase + c8];
            *(us8*)&ks[row * 264 + c8] = *(const us8*)&kp[(size_t)row * HW + kbase + c8];
        }
        __syncthreads();
#pragma unroll
        for (int s = 0; s < 2; ++s) {
            int ko = (wv * 2 + s) * 32 + quad * 8;
            bf16x8 qa0 = *(const bf16x8*)&qs[l15 * 264 + ko];
            bf16x8 qa1 = hi ? *(const bf16x8*)&qs[(16 + l15) * 264 + ko] : z;
            bf16x8 kb0 = *(const bf16x8*)&ks[l15 * 264 + ko];
            bf16x8 kb1 = hi ? *(const bf16x8*)&ks[(16 + l15) * 264 + ko] : z;
            a00 = __builtin_amdgcn_mfma_f32_16x16x32_bf16(qa0, kb0, a00, 0, 0, 0);
            a01 = __builtin_amdgcn_mfma_f32_16x16x32_bf16(qa0, kb1, a01, 0, 0, 0);
            a10 = __builtin_amdgcn_mfma_f32_16x16x32_bf16(qa1, kb0, a10, 0, 0, 0);
            a11 = __builtin_amdgcn_mfma_f32_16x16x32_bf16(qa1, kb1, a11, 0, 0, 0);
        }
        __syncthreads();
    }
    float* Gp = G + (size_t)bh * 576;
#pragma unroll
    for (int r = 0; r < 4; ++r) {
        int r0 = quad * 4 + r, r1 = 16 + quad * 4 + r;
        int c0 = l15, c1 = 16 + l15;
        atomicAdd(&Gp[r0 * 24 + c0], a00[r]);
        if (c1 < 24) atomicAdd(&Gp[r0 * 24 + c1], a01[r]);
        if (r1 < 24) atomicAdd(&Gp[r1 * 24 + c0], a10[r]);
        if (r1 < 24 && c1 < 24) atomicAdd(&Gp[r1 * 24 + c1], a11[r]);
    }
}

// ---------------------------------------------------------------------------
// K5: softmax(P) per (b,h) and Weff[b] = W_proj * blockdiag(P)  (Weff bf16)
// grid (8, 24); variance computed inline from (S1,S2) partial sums
// ---------------------------------------------------------------------------
__global__ __launch_bounds__(256) void k_smweff(const float* __restrict__ G,
                                                const float* __restrict__ ssq,
                                                const float* __restrict__ vs1,
                                                const float* __restrict__ vs2,
                                                const float* __restrict__ wproj,
                                                const float* __restrict__ temp,
                                                const float* __restrict__ resc,
                                                ushort_t* __restrict__ Weff) {
    int b = blockIdx.x, t = threadIdx.x;
    __shared__ float P[8 * 24 * 24];
    __shared__ float snq[192], snk[192];
    if (t < 192) {
        snq[t] = fmaxf(sqrtf(ssq[b * 384 + t]), 1e-12f);
        snk[t] = fmaxf(sqrtf(ssq[b * 384 + 192 + t]), 1e-12f);
    }
    __syncthreads();
    if (t < 192) {
        int h = t / 24, c = t % 24;
        float tmpv = temp[h];
        float S1 = vs1[b * 192 + t], S2 = vs2[b * 192 + t];
        float varv = (S2 - S1 * S1 * (1.0f / 16384.f)) * (1.0f / 16383.f);
        float dvar = resc[h] * varv;
        const float* Gp = G + (size_t)(b * 8 + h) * 576 + c * 24;
        float inq = tmpv / snq[t];
        float lg[24]; float mx = -1e30f;
#pragma unroll
        for (int d = 0; d < 24; ++d) {
            float v = Gp[d] * inq / snk[h * 24 + d];
            if (d == c) v += dvar;
            lg[d] = v; mx = fmaxf(mx, v);
        }
        float sum = 0.f;
#pragma unroll
        for (int d = 0; d < 24; ++d) { float e = __expf(lg[d] - mx); lg[d] = e; sum += e; }
        float inv = 1.f / sum;
#pragma unroll
        for (int d = 0; d < 24; ++d) P[(h * 24 + c) * 24 + d] = lg[d] * inv;
    }
    __syncthreads();
#pragma unroll
    for (int i = 0; i < 6; ++i) {
        int idx = t + (blockIdx.y * 6 + i) * 256;
        int co = idx / 192, hd = idx % 192;
        int h2 = hd / 24, d = hd % 24;
        float a = 0.f;
#pragma unroll
        for (int c2 = 0; c2 < 24; ++c2)
            a += wproj[co * 192 + h2 * 24 + c2] * P[(h2 * 24 + c2) * 24 + d];
        Weff[(size_t)b * 36864 + idx] = f2b(a);
    }
}

// ---------------------------------------------------------------------------
extern "C" void kernel_launch(void* const* d_in, const int* in_sizes, int n_in,
                              void* d_out, int out_size, void* d_ws, size_t ws_size,
                              hipStream_t stream) {
    const float* x      = (const float*)d_in[0];
    const float* wdw    = (const float*)d_in[1];
    const float* wqkv   = (const float*)d_in[2];
    const float* wqkvdw = (const float*)d_in[3];
    const float* wproj  = (const float*)d_in[4];
    const float* temp   = (const float*)d_in[5];
    const float* resc   = (const float*)d_in[6];
    float* out = (float*)d_out;

    char* ws = (char*)d_ws;
    ushort_t* qkvraw = (ushort_t*)ws;                              // 150,994,944 B (bf16)
    ushort_t* qkvd   = (ushort_t*)(ws + 150994944);                // 150,994,944 B (bf16)
    char* small = ws + 301989888;
    float* vs1  = (float*)small;                                   // 6,144 B (zeroed)
    float* vs2  = (float*)(small + 6144);                          // 6,144 B (zeroed)
    float* ssq  = (float*)(small + 12288);                         // 12,288 B (zeroed)
    float* G    = (float*)(small + 24576);                         // 147,456 B (zeroed)
    ushort_t* Weff = (ushort_t*)(small + 172032);                  // 589,824 B

    // xb (bf16 x, 50.3 MB) aliases qkvd start; wqb (bf16 wqkv, 221 KB) aliases
    // qkvd tail (offset 120 MB) — both dead before k_dwqkv overwrites qkvd
    ushort_t* xb  = qkvd;
    ushort_t* wqb = qkvd + 60000000;

    (void)hipMemsetAsync(small, 0, 172032, stream);
    k_cvt<<<dim3(54), dim3(256), 0, stream>>>(wqkv, wqb, 13824);
    k_dwvar<<<dim3(3072), dim3(256), 0, stream>>>(x, wdw, vs1, vs2, xb);
    k_gemm<0><<<dim3(128, 3, 8), dim3(256), 0, stream>>>(wqb, 0L, xb, 3145728L, qkvraw, 9437184L, 192);
    k_dwqkv<<<dim3(9216), dim3(256), 0, stream>>>(qkvraw, wqkvdw, qkvd, ssq);
    k_gram<<<dim3(8, 64), dim3(256), 0, stream>>>(qkvd, G);
    k_smweff<<<dim3(8, 24), dim3(256), 0, stream>>>(G, ssq, vs1, vs2, wproj, temp, resc, Weff);
    k_gemm<1><<<dim3(128, 1, 8), dim3(256), 0, stream>>>(Weff, 36864L, qkvd + (size_t)384 * HW, 9437184L, out, 3145728L, 192);
}

// Round 7
// 362.729 us; speedup vs baseline: 1.1190x; 1.0065x over previous
//
#include <hip/hip_runtime.h>
#include <hip/hip_bf16.h>

typedef unsigned short ushort_t;
typedef __bf16 bf16x8 __attribute__((ext_vector_type(8)));
typedef float f32x4 __attribute__((ext_vector_type(4)));
typedef unsigned short us8 __attribute__((ext_vector_type(8)));
typedef unsigned short us4 __attribute__((ext_vector_type(4)));

#define HW 16384
#define CDIM 192
#define QKVC 576

static __device__ __forceinline__ float b2f(unsigned short u) {
    union { unsigned int i; float f; } cv; cv.i = ((unsigned int)u) << 16; return cv.f;
}
static __device__ __forceinline__ unsigned short f2b(float f) {
    union { __bf16 h; unsigned short u; } cv; cv.h = (__bf16)f; return cv.u;
}

// ---------------------------------------------------------------------------
// K0: one-time fp32 -> bf16 convert (wqkv weights), 8 elems/thread
// ---------------------------------------------------------------------------
__global__ __launch_bounds__(256) void k_cvt(const float* __restrict__ src,
                                             ushort_t* __restrict__ dst, int n8) {
    int i = blockIdx.x * 256 + threadIdx.x;
    if (i >= n8) return;
    f32x4 a = *(const f32x4*)&src[i * 8];
    f32x4 b = *(const f32x4*)&src[i * 8 + 4];
    us8 o;
#pragma unroll
    for (int e = 0; e < 4; ++e) { o[e] = f2b(a[e]); o[4 + e] = f2b(b[e]); }
    *(us8*)&dst[i * 8] = o;
}

// ---------------------------------------------------------------------------
// K1: depthwise 3x3 (fp32) on x, HALF-plane per block (64 rows + 2 halo)
// pipelined vector loads: NO scalar LDS reads (all f32x4, conflict-free)
// ---------------------------------------------------------------------------
__global__ __launch_bounds__(256) void k_dwvar(const float* __restrict__ x,
                                               const float* __restrict__ wdw,
                                               float* __restrict__ vs1,
                                               float* __restrict__ vs2,
                                               ushort_t* __restrict__ xb) {
    __shared__ __align__(16) float pl[66 * 132];    // LDS row i = plane row rb+i-1
    __shared__ float red[8];
    int blk = blockIdx.x;
    int bc = blk >> 1, half = blk & 1, rb = half * 64;
    int c = bc % CDIM;
    const float* xp = x + (size_t)bc * HW;
    ushort_t* xbp = xb + (size_t)bc * HW;
    int t = threadIdx.x;
#pragma unroll
    for (int i = 0; i < 8; ++i) {
        int gi = t + i * 256;            // f32x4 granule [0,2048)
        int row = gi >> 5, q4 = (gi & 31) * 4;
        f32x4 v4 = *(const f32x4*)&xp[(size_t)(rb + row) * 128 + q4];
        *(f32x4*)&pl[(row + 1) * 132 + q4] = v4;
        us4 b4;
#pragma unroll
        for (int j = 0; j < 4; ++j) b4[j] = f2b(v4[j]);
        *(us4*)&xbp[(size_t)(rb + row) * 128 + q4] = b4;
    }
    if (t < 32) {                        // top halo (plane row rb-1 or zeros)
        f32x4 v = {0.f, 0.f, 0.f, 0.f};
        if (rb > 0) v = *(const f32x4*)&xp[(size_t)(rb - 1) * 128 + t * 4];
        *(f32x4*)&pl[t * 4] = v;
    } else if (t < 64) {                 // bottom halo (plane row rb+64 or zeros)
        int g = t - 32;
        f32x4 v = {0.f, 0.f, 0.f, 0.f};
        if (rb + 64 < 128) v = *(const f32x4*)&xp[(size_t)(rb + 64) * 128 + g * 4];
        *(f32x4*)&pl[65 * 132 + g * 4] = v;
    }
    float w[9];
#pragma unroll
    for (int j = 0; j < 9; ++j) w[j] = wdw[c * 9 + j];
    __syncthreads();

    int lane = t & 63, wv = t >> 6;
    int y = lane, xs = wv * 32;          // output row rb+y, cols [xs, xs+32)
    int yb0 = y * 132, yb1 = yb0 + 132, yb2 = yb1 + 132;
    float l0 = 0.f, l1 = 0.f, l2 = 0.f;
    if (xs != 0) {                       // left halo via vector read, take [3]
        f32x4 h0 = *(const f32x4*)&pl[yb0 + xs - 4];
        f32x4 h1 = *(const f32x4*)&pl[yb1 + xs - 4];
        f32x4 h2 = *(const f32x4*)&pl[yb2 + xs - 4];
        l0 = h0[3]; l1 = h1[3]; l2 = h2[3];
    }
    f32x4 a0 = *(const f32x4*)&pl[yb0 + xs], b0 = *(const f32x4*)&pl[yb0 + xs + 4];
    f32x4 a1 = *(const f32x4*)&pl[yb1 + xs], b1 = *(const f32x4*)&pl[yb1 + xs + 4];
    f32x4 a2 = *(const f32x4*)&pl[yb2 + xs], b2 = *(const f32x4*)&pl[yb2 + xs + 4];
    float s1 = 0.f, s2 = 0.f;
#pragma unroll
    for (int g = 0; g < 4; ++g) {
        int x0 = xs + g * 8;
        f32x4 na0, nb0, na1, nb1, na2, nb2;
        float e9_0, e9_1, e9_2;
        if (g < 3) {                     // pipeline: next group's vectors
            na0 = *(const f32x4*)&pl[yb0 + x0 + 8]; nb0 = *(const f32x4*)&pl[yb0 + x0 + 12];
            na1 = *(const f32x4*)&pl[yb1 + x0 + 8]; nb1 = *(const f32x4*)&pl[yb1 + x0 + 12];
            na2 = *(const f32x4*)&pl[yb2 + x0 + 8]; nb2 = *(const f32x4*)&pl[yb2 + x0 + 12];
            e9_0 = na0[0]; e9_1 = na1[0]; e9_2 = na2[0];
        } else {
            e9_0 = e9_1 = e9_2 = 0.f;
            if (xs + 32 < 128) {         // right boundary via vector read, take [0]
                f32x4 q0 = *(const f32x4*)&pl[yb0 + xs + 32];
                f32x4 q1 = *(const f32x4*)&pl[yb1 + xs + 32];
                f32x4 q2 = *(const f32x4*)&pl[yb2 + xs + 32];
                e9_0 = q0[0]; e9_1 = q1[0]; e9_2 = q2[0];
            }
        }
        float e0[10], e1[10], e2[10];
        e0[0] = l0; e1[0] = l1; e2[0] = l2;
#pragma unroll
        for (int j = 0; j < 4; ++j) {
            e0[1 + j] = a0[j]; e0[5 + j] = b0[j];
            e1[1 + j] = a1[j]; e1[5 + j] = b1[j];
            e2[1 + j] = a2[j]; e2[5 + j] = b2[j];
        }
        e0[9] = e9_0; e1[9] = e9_1; e2[9] = e9_2;
#pragma unroll
        for (int j = 0; j < 8; ++j) {
            float o = e0[j] * w[0] + e0[j + 1] * w[1] + e0[j + 2] * w[2]
                    + e1[j] * w[3] + e1[j + 1] * w[4] + e1[j + 2] * w[5]
                    + e2[j] * w[6] + e2[j + 1] * w[7] + e2[j + 2] * w[8];
            s1 += o; s2 += o * o;
        }
        l0 = e0[8]; l1 = e1[8]; l2 = e2[8];
        if (g < 3) { a0 = na0; b0 = nb0; a1 = na1; b1 = nb1; a2 = na2; b2 = nb2; }
    }
#pragma unroll
    for (int off = 32; off; off >>= 1) { s1 += __shfl_xor(s1, off); s2 += __shfl_xor(s2, off); }
    if (lane == 0) { red[wv * 2] = s1; red[wv * 2 + 1] = s2; }
    __syncthreads();
    if (t == 0) {
        atomicAdd(&vs1[bc], red[0] + red[2] + red[4] + red[6]);
        atomicAdd(&vs2[bc], red[1] + red[3] + red[5] + red[7]);
    }
}

// ---------------------------------------------------------------------------
// K3: depthwise 3x3 on qkv planes, HALF-plane per block (64 rows + 2 halo)
// pipelined us8 loads: NO scalar LDS reads; ssq from unrounded conv output
// ---------------------------------------------------------------------------
__global__ __launch_bounds__(256) void k_dwqkv(const ushort_t* __restrict__ qkvraw,
                                               const float* __restrict__ wqd,
                                               ushort_t* __restrict__ qkvd,
                                               float* __restrict__ ssq) {
    __shared__ __align__(16) ushort_t pl[66 * 136];
    __shared__ float red[4];
    int blk = blockIdx.x;
    int bo = blk >> 1, half = blk & 1, rb = half * 64;
    int o = bo % QKVC, b = bo / QKVC;
    const ushort_t* xp = qkvraw + (size_t)bo * HW;
    ushort_t* op = qkvd + (size_t)bo * HW;
    int t = threadIdx.x;
#pragma unroll
    for (int i = 0; i < 4; ++i) {
        int gi = t + i * 256;            // us8 granule [0,1024)
        int row = gi >> 4, gr = (gi & 15) * 8;
        *(us8*)&pl[(row + 1) * 136 + gr] = *(const us8*)&xp[(size_t)(rb + row) * 128 + gr];
    }
    if (t < 16) {                        // top halo
        us8 v = {};
        if (rb > 0) v = *(const us8*)&xp[(size_t)(rb - 1) * 128 + t * 8];
        *(us8*)&pl[t * 8] = v;
    } else if (t < 32) {                 // bottom halo
        int g = t - 16;
        us8 v = {};
        if (rb + 64 < 128) v = *(const us8*)&xp[(size_t)(rb + 64) * 128 + g * 8];
        *(us8*)&pl[65 * 136 + g * 8] = v;
    }
    float w[9];
#pragma unroll
    for (int j = 0; j < 9; ++j) w[j] = wqd[o * 9 + j];
    __syncthreads();

    int lane = t & 63, wv = t >> 6;
    int y = lane, xs = wv * 32;
    int yb0 = y * 136, yb1 = yb0 + 136, yb2 = yb1 + 136;
    float l0 = 0.f, l1 = 0.f, l2 = 0.f;
    if (xs != 0) {                       // left halo via us8 read, take [7]
        us8 h0 = *(const us8*)&pl[yb0 + xs - 8];
        us8 h1 = *(const us8*)&pl[yb1 + xs - 8];
        us8 h2 = *(const us8*)&pl[yb2 + xs - 8];
        l0 = b2f(h0[7]); l1 = b2f(h1[7]); l2 = b2f(h2[7]);
    }
    us8 c0 = *(const us8*)&pl[yb0 + xs];
    us8 c1 = *(const us8*)&pl[yb1 + xs];
    us8 c2 = *(const us8*)&pl[yb2 + xs];
    float s2 = 0.f;
#pragma unroll
    for (int g = 0; g < 4; ++g) {
        int x0 = xs + g * 8;
        us8 n0, n1, n2;
        float e9_0, e9_1, e9_2;
        if (g < 3) {                     // pipeline: next group's vectors
            n0 = *(const us8*)&pl[yb0 + x0 + 8];
            n1 = *(const us8*)&pl[yb1 + x0 + 8];
            n2 = *(const us8*)&pl[yb2 + x0 + 8];
            e9_0 = b2f(n0[0]); e9_1 = b2f(n1[0]); e9_2 = b2f(n2[0]);
        } else {
            e9_0 = e9_1 = e9_2 = 0.f;
            if (xs + 32 < 128) {         // right boundary via us8 read, take [0]
                us8 q0 = *(const us8*)&pl[yb0 + xs + 32];
                us8 q1 = *(const us8*)&pl[yb1 + xs + 32];
                us8 q2 = *(const us8*)&pl[yb2 + xs + 32];
                e9_0 = b2f(q0[0]); e9_1 = b2f(q1[0]); e9_2 = b2f(q2[0]);
            }
        }
        float e0[10], e1[10], e2[10];
        e0[0] = l0; e1[0] = l1; e2[0] = l2;
#pragma unroll
        for (int j = 0; j < 8; ++j) { e0[j + 1] = b2f(c0[j]); e1[j + 1] = b2f(c1[j]); e2[j + 1] = b2f(c2[j]); }
        e0[9] = e9_0; e1[9] = e9_1; e2[9] = e9_2;
        us8 ob;
#pragma unroll
        for (int j = 0; j < 8; ++j) {
            float ov = e0[j] * w[0] + e0[j + 1] * w[1] + e0[j + 2] * w[2]
                     + e1[j] * w[3] + e1[j + 1] * w[4] + e1[j + 2] * w[5]
                     + e2[j] * w[6] + e2[j + 1] * w[7] + e2[j + 2] * w[8];
            ob[j] = f2b(ov);
            s2 += ov * ov;               // unrounded: closer to fp32 reference norm
        }
        *(us8*)&op[(size_t)(rb + y) * 128 + x0] = ob;
        l0 = e0[8]; l1 = e1[8]; l2 = e2[8];
        if (g < 3) { c0 = n0; c1 = n1; c2 = n2; }
    }
#pragma unroll
    for (int off = 32; off; off >>= 1) s2 += __shfl_xor(s2, off);
    if (lane == 0) red[wv] = s2;
    __syncthreads();
    if (t == 0 && o < 2 * CDIM)
        atomicAdd(&ssq[b * 384 + o], red[0] + red[1] + red[2] + red[3]);
}

// ---------------------------------------------------------------------------
// GEMM: C[b] = A[b] (MxK bf16, row-major) * B[b] (KxN bf16, N contiguous)
// BM=192 BN=128 BK=64; 4 waves x 3 row-tiles x 8 col-tiles; 16x16x32 bf16
// As: row-XOR swizzle. Bs: granule swizzle (verified conflict-free, R3 PMC=0)
// B register-prefetch (k+1 under MFMA of k) + LDS-staged coalesced C epilogue
// ---------------------------------------------------------------------------
template<int CF>
__global__ __launch_bounds__(256) void k_gemm(const ushort_t* __restrict__ Av, long sAb,
                                              const ushort_t* __restrict__ Bv, long sBb,
                                              void* __restrict__ Cv, long sCb, int K) {
    __shared__ __align__(16) char smem[49152];
    ushort_t* As = (ushort_t*)smem;                 // [192][64] bf16, row-XOR swizzled
    ushort_t* Bs = (ushort_t*)(smem + 24576);       // [128][64] bf16, granule swizzled
    int t = threadIdx.x;
    int wv = t >> 6, lane = t & 63, quad = lane >> 4, l15 = lane & 15;
    size_t aoff = (size_t)blockIdx.z * sAb + (size_t)blockIdx.y * 192 * K;
    size_t boff = (size_t)blockIdx.z * sBb + (size_t)blockIdx.x * 128;
    size_t coff = (size_t)blockIdx.z * sCb + (size_t)blockIdx.y * 192 * HW + (size_t)blockIdx.x * 128;
    f32x4 acc[24] = {};
    int bkr = t >> 3, bn0 = (t & 7) * 16, tlow = t & 7;
    int gk0 = bkr >> 3, klo = bkr & 7;
    const ushort_t* Bp = Bv + boff;
    us8 pb0 = *(const us8*)&Bp[(size_t)bkr * HW + bn0];
    us8 pb1 = *(const us8*)&Bp[(size_t)bkr * HW + bn0 + 8];
    us8 pb2 = *(const us8*)&Bp[(size_t)(bkr + 32) * HW + bn0];
    us8 pb3 = *(const us8*)&Bp[(size_t)(bkr + 32) * HW + bn0 + 8];
    int nIter = K >> 6;
    for (int it = 0; it < nIter; ++it) {
        int kk = it << 6;
#pragma unroll
        for (int i = 0; i < 6; ++i) {
            int s = t + i * 256;                   // [0,1536)
            int row = s >> 3, kc = (s & 7) * 8;
            int kcs = kc ^ ((row & 7) * 8);
            *(uint4*)&As[row * 64 + kcs] = *(const uint4*)&Av[aoff + (size_t)row * K + kk + kc];
        }
#pragma unroll
        for (int e = 0; e < 8; ++e) {
            int col0 = ((gk0 ^ tlow ^ e) << 3) + klo;
            Bs[(bn0 + e) * 64 + col0] = pb0[e];
            Bs[(bn0 + 8 + e) * 64 + col0] = pb1[e];
            int col1 = (((gk0 + 4) ^ tlow ^ e) << 3) + klo;
            Bs[(bn0 + e) * 64 + col1] = pb2[e];
            Bs[(bn0 + 8 + e) * 64 + col1] = pb3[e];
        }
        __syncthreads();
        if (it + 1 < nIter) {
            const ushort_t* Bn = &Bp[(size_t)(kk + 64) * HW];
            pb0 = *(const us8*)&Bn[(size_t)bkr * HW + bn0];
            pb1 = *(const us8*)&Bn[(size_t)bkr * HW + bn0 + 8];
            pb2 = *(const us8*)&Bn[(size_t)(bkr + 32) * HW + bn0];
            pb3 = *(const us8*)&Bn[(size_t)(bkr + 32) * HW + bn0 + 8];
        }
#pragma unroll
        for (int s = 0; s < 2; ++s) {
            int r0 = wv * 16 + l15, r1 = 64 + r0, r2 = 128 + r0;
            int ko = s * 32 + quad * 8;
            bf16x8 af0 = *(const bf16x8*)&As[r0 * 64 + (ko ^ ((r0 & 7) * 8))];
            bf16x8 af1 = *(const bf16x8*)&As[r1 * 64 + (ko ^ ((r1 & 7) * 8))];
            bf16x8 af2 = *(const bf16x8*)&As[r2 * 64 + (ko ^ ((r2 & 7) * 8))];
#pragma unroll
            for (int tc = 0; tc < 8; ++tc) {
                int n = tc * 16 + l15;
                int g = (s * 4 + quad) ^ ((tc ^ l15) & 7);
                bf16x8 bfr = *(const bf16x8*)&Bs[n * 64 + (g << 3)];
                acc[tc]      = __builtin_amdgcn_mfma_f32_16x16x32_bf16(af0, bfr, acc[tc],      0, 0, 0);
                acc[8 + tc]  = __builtin_amdgcn_mfma_f32_16x16x32_bf16(af1, bfr, acc[8 + tc],  0, 0, 0);
                acc[16 + tc] = __builtin_amdgcn_mfma_f32_16x16x32_bf16(af2, bfr, acc[16 + tc], 0, 0, 0);
            }
        }
        __syncthreads();
    }
    if (CF == 0) {
        ushort_t* Ct = (ushort_t*)smem;            // 192*128*2 = 49152
#pragma unroll
        for (int rt = 0; rt < 3; ++rt)
#pragma unroll
            for (int tc = 0; tc < 8; ++tc)
#pragma unroll
                for (int r = 0; r < 4; ++r)
                    Ct[(rt * 64 + wv * 16 + quad * 4 + r) * 128 + tc * 16 + l15] = f2b(acc[rt * 8 + tc][r]);
        __syncthreads();
        ushort_t* Co = (ushort_t*)Cv;
#pragma unroll
        for (int i = 0; i < 12; ++i) {
            int s = t + i * 256;                   // [0,3072)
            int row = s >> 4, c8 = (s & 15) * 8;
            *(us8*)&Co[coff + (size_t)row * HW + c8] = *(us8*)&Ct[row * 128 + c8];
        }
    } else {
        float* Cf = (float*)smem;                  // 64*128*4 = 32768 per pass
        float* Co = (float*)Cv;
#pragma unroll
        for (int rt = 0; rt < 3; ++rt) {
            if (rt) __syncthreads();
#pragma unroll
            for (int tc = 0; tc < 8; ++tc)
#pragma unroll
                for (int r = 0; r < 4; ++r)
                    Cf[(wv * 16 + quad * 4 + r) * 128 + tc * 16 + l15] = acc[rt * 8 + tc][r];
            __syncthreads();
#pragma unroll
            for (int i = 0; i < 8; ++i) {
                int s = t + i * 256;               // [0,2048)
                int row = s >> 5, c4 = (s & 31) * 4;
                *(f32x4*)&Co[coff + (size_t)(rt * 64 + row) * HW + c4] = *(f32x4*)&Cf[row * 128 + c4];
            }
        }
    }
}

// ---------------------------------------------------------------------------
// K4: Gram G[b,h] = q . k^T (24x24, K=16384), LDS-staged, mfma, atomic combine
// ---------------------------------------------------------------------------
__global__ __launch_bounds__(256) void k_gram(const ushort_t* __restrict__ qkvd,
                                              float* __restrict__ G) {
    __shared__ __align__(16) ushort_t qs[24 * 264];
    __shared__ __align__(16) ushort_t ks[24 * 264];
    int bh = blockIdx.y;
    int b = bh >> 3, h = bh & 7;
    int t = threadIdx.x, wv = t >> 6, lane = t & 63, quad = lane >> 4, l15 = lane & 15;
    const ushort_t* qb = qkvd + (size_t)b * 9437184 + (size_t)(h * 24) * HW;
    const ushort_t* kp = qb + (size_t)CDIM * HW;
    f32x4 a00 = {}, a01 = {}, a10 = {}, a11 = {};
    bf16x8 z = {};
    bool hi = (l15 < 8);
    int kbase0 = blockIdx.x * 2048;
    for (int sub = 0; sub < 8; ++sub) {
        int kbase = kbase0 + sub * 256;
#pragma unroll
        for (int j = 0; j < 3; ++j) {
            int gi = t + j * 256;       // [0,768)
            int row = gi >> 5, c8 = (gi & 31) * 8;
            *(us8*)&qs[row * 264 + c8] = *(const us8*)&qb[(size_t)row * HW + kbase + c8];
            *(us8*)&ks[row * 264 + c8] = *(const us8*)&kp[(size_t)row * HW + kbase + c8];
        }
        __syncthreads();
#pragma unroll
        for (int s = 0; s < 2; ++s) {
            int ko = (wv * 2 + s) * 32 + quad * 8;
            bf16x8 qa0 = *(const bf16x8*)&qs[l15 * 264 + ko];
            bf16x8 qa1 = hi ? *(const bf16x8*)&qs[(16 + l15) * 264 + ko] : z;
            bf16x8 kb0 = *(const bf16x8*)&ks[l15 * 264 + ko];
            bf16x8 kb1 = hi ? *(const bf16x8*)&ks[(16 + l15) * 264 + ko] : z;
            a00 = __builtin_amdgcn_mfma_f32_16x16x32_bf16(qa0, kb0, a00, 0, 0, 0);
            a01 = __builtin_amdgcn_mfma_f32_16x16x32_bf16(qa0, kb1, a01, 0, 0, 0);
            a10 = __builtin_amdgcn_mfma_f32_16x16x32_bf16(qa1, kb0, a10, 0, 0, 0);
            a11 = __builtin_amdgcn_mfma_f32_16x16x32_bf16(qa1, kb1, a11, 0, 0, 0);
        }
        __syncthreads();
    }
    float* Gp = G + (size_t)bh * 576;
#pragma unroll
    for (int r = 0; r < 4; ++r) {
        int r0 = quad * 4 + r, r1 = 16 + quad * 4 + r;
        int c0 = l15, c1 = 16 + l15;
        atomicAdd(&Gp[r0 * 24 + c0], a00[r]);
        if (c1 < 24) atomicAdd(&Gp[r0 * 24 + c1], a01[r]);
        if (r1 < 24) atomicAdd(&Gp[r1 * 24 + c0], a10[r]);
        if (r1 < 24 && c1 < 24) atomicAdd(&Gp[r1 * 24 + c1], a11[r]);
    }
}

// ---------------------------------------------------------------------------
// K5: softmax(P) per (b,h) and Weff[b] = W_proj * blockdiag(P)  (Weff bf16)
// grid (8, 24); variance computed inline from (S1,S2) partial sums
// ---------------------------------------------------------------------------
__global__ __launch_bounds__(256) void k_smweff(const float* __restrict__ G,
                                                const float* __restrict__ ssq,
                                                const float* __restrict__ vs1,
                                                const float* __restrict__ vs2,
                                                const float* __restrict__ wproj,
                                                const float* __restrict__ temp,
                                                const float* __restrict__ resc,
                                                ushort_t* __restrict__ Weff) {
    int b = blockIdx.x, t = threadIdx.x;
    __shared__ float P[8 * 24 * 24];
    __shared__ float snq[192], snk[192];
    if (t < 192) {
        snq[t] = fmaxf(sqrtf(ssq[b * 384 + t]), 1e-12f);
        snk[t] = fmaxf(sqrtf(ssq[b * 384 + 192 + t]), 1e-12f);
    }
    __syncthreads();
    if (t < 192) {
        int h = t / 24, c = t % 24;
        float tmpv = temp[h];
        float S1 = vs1[b * 192 + t], S2 = vs2[b * 192 + t];
        float varv = (S2 - S1 * S1 * (1.0f / 16384.f)) * (1.0f / 16383.f);
        float dvar = resc[h] * varv;
        const float* Gp = G + (size_t)(b * 8 + h) * 576 + c * 24;
        float inq = tmpv / snq[t];
        float lg[24]; float mx = -1e30f;
#pragma unroll
        for (int d = 0; d < 24; ++d) {
            float v = Gp[d] * inq / snk[h * 24 + d];
            if (d == c) v += dvar;
            lg[d] = v; mx = fmaxf(mx, v);
        }
        float sum = 0.f;
#pragma unroll
        for (int d = 0; d < 24; ++d) { float e = __expf(lg[d] - mx); lg[d] = e; sum += e; }
        float inv = 1.f / sum;
#pragma unroll
        for (int d = 0; d < 24; ++d) P[(h * 24 + c) * 24 + d] = lg[d] * inv;
    }
    __syncthreads();
#pragma unroll
    for (int i = 0; i < 6; ++i) {
        int idx = t + (blockIdx.y * 6 + i) * 256;
        int co = idx / 192, hd = idx % 192;
        int h2 = hd / 24, d = hd % 24;
        float a = 0.f;
#pragma unroll
        for (int c2 = 0; c2 < 24; ++c2)
            a += wproj[co * 192 + h2 * 24 + c2] * P[(h2 * 24 + c2) * 24 + d];
        Weff[(size_t)b * 36864 + idx] = f2b(a);
    }
}

// ---------------------------------------------------------------------------
extern "C" void kernel_launch(void* const* d_in, const int* in_sizes, int n_in,
                              void* d_out, int out_size, void* d_ws, size_t ws_size,
                              hipStream_t stream) {
    const float* x      = (const float*)d_in[0];
    const float* wdw    = (const float*)d_in[1];
    const float* wqkv   = (const float*)d_in[2];
    const float* wqkvdw = (const float*)d_in[3];
    const float* wproj  = (const float*)d_in[4];
    const float* temp   = (const float*)d_in[5];
    const float* resc   = (const float*)d_in[6];
    float* out = (float*)d_out;

    char* ws = (char*)d_ws;
    ushort_t* qkvraw = (ushort_t*)ws;                              // 150,994,944 B (bf16)
    ushort_t* qkvd   = (ushort_t*)(ws + 150994944);                // 150,994,944 B (bf16)
    char* small = ws + 301989888;
    float* vs1  = (float*)small;                                   // 6,144 B (zeroed)
    float* vs2  = (float*)(small + 6144);                          // 6,144 B (zeroed)
    float* ssq  = (float*)(small + 12288);                         // 12,288 B (zeroed)
    float* G    = (float*)(small + 24576);                         // 147,456 B (zeroed)
    ushort_t* Weff = (ushort_t*)(small + 172032);                  // 589,824 B

    // xb (bf16 x, 50.3 MB) aliases qkvd start; wqb (bf16 wqkv, 221 KB) aliases
    // qkvd tail (offset 120 MB) — both dead before k_dwqkv overwrites qkvd
    ushort_t* xb  = qkvd;
    ushort_t* wqb = qkvd + 60000000;

    (void)hipMemsetAsync(small, 0, 172032, stream);
    k_cvt<<<dim3(54), dim3(256), 0, stream>>>(wqkv, wqb, 13824);
    k_dwvar<<<dim3(3072), dim3(256), 0, stream>>>(x, wdw, vs1, vs2, xb);
    k_gemm<0><<<dim3(128, 3, 8), dim3(256), 0, stream>>>(wqb, 0L, xb, 3145728L, qkvraw, 9437184L, 192);
    k_dwqkv<<<dim3(9216), dim3(256), 0, stream>>>(qkvraw, wqkvdw, qkvd, ssq);
    k_gram<<<dim3(8, 64), dim3(256), 0, stream>>>(qkvd, G);
    k_smweff<<<dim3(8, 24), dim3(256), 0, stream>>>(G, ssq, vs1, vs2, wproj, temp, resc, Weff);
    k_gemm<1><<<dim3(128, 1, 8), dim3(256), 0, stream>>>(Weff, 36864L, qkvd + (size_t)384 * HW, 9437184L, out, 3145728L, 192);
}